// Round 9
// baseline (1399.388 us; speedup 1.0000x reference)
//
#include <hip/hip_runtime.h>
#include <math.h>

#define DOUT 128

typedef unsigned short u16;
typedef __attribute__((ext_vector_type(8))) short bf16x8;   // 8 bf16 bit-patterns (4 VGPRs)
typedef __attribute__((ext_vector_type(4))) float f32x4;

static __device__ __forceinline__ f32x4 mfma16x16x32(bf16x8 a, bf16x8 b, f32x4 c) {
  return __builtin_amdgcn_mfma_f32_16x16x32_bf16(a, b, c, 0, 0, 0);
}

static __device__ __forceinline__ short bf16i(int v) {   // exact for |v| <= 256
  return (short)(__float_as_uint((float)v) >> 16);
}

// ---------- wave (64-lane) reductions ----------
static __device__ __forceinline__ float wsum64(float v) {
#pragma unroll
  for (int off = 32; off > 0; off >>= 1) v += __shfl_xor(v, off, 64);
  return v;
}
static __device__ __forceinline__ float wmax64(float v) {
#pragma unroll
  for (int off = 32; off > 0; off >>= 1) v = fmaxf(v, __shfl_xor(v, off, 64));
  return v;
}
// sum across the 4 lanes sharing (lane&15)  (lane bits 4,5)
static __device__ __forceinline__ float rsumg(float v) {
  v += __shfl_xor(v, 16, 64);
  v += __shfl_xor(v, 32, 64);
  return v;
}

// 3-way RNE bf16 split: x == h + m + l + eps, |eps| <= 2^-25 |x|  (manual, cold path)
static __device__ __forceinline__ void split3(float x, u16& h, u16& m, u16& l) {
  unsigned u = __float_as_uint(x);
  unsigned rh = u + 0x7FFFu + ((u >> 16) & 1u);
  h = (u16)(rh >> 16);
  float hf = __uint_as_float(rh & 0xFFFF0000u);
  float d1 = x - hf;
  unsigned v = __float_as_uint(d1);
  unsigned rm = v + 0x7FFFu + ((v >> 16) & 1u);
  m = (u16)(rm >> 16);
  float mf = __uint_as_float(rm & 0xFFFF0000u);
  float d2 = d1 - mf;
  unsigned w2 = __float_as_uint(d2);
  unsigned rl = w2 + 0x7FFFu + ((w2 >> 16) & 1u);
  l = (u16)(rl >> 16);
}

// hot-path split via v_cvt_pk_bf16_f32 (HW RNE; packs lo=cvt(x0), hi=cvt(x1))
static __device__ __forceinline__ void split3pk(float x0, float x1,
                                                unsigned& h, unsigned& m, unsigned& l) {
  unsigned hp, mp, lp;
  asm("v_cvt_pk_bf16_f32 %0, %1, %2" : "=v"(hp) : "v"(x0), "v"(x1));
  float d0 = x0 - __uint_as_float(hp << 16);
  float d1 = x1 - __uint_as_float(hp & 0xFFFF0000u);
  asm("v_cvt_pk_bf16_f32 %0, %1, %2" : "=v"(mp) : "v"(d0), "v"(d1));
  float e0 = d0 - __uint_as_float(mp << 16);
  float e1 = d1 - __uint_as_float(mp & 0xFFFF0000u);
  asm("v_cvt_pk_bf16_f32 %0, %1, %2" : "=v"(lp) : "v"(e0), "v"(e1));
  h = hp; m = mp; l = lp;
}
static __device__ __forceinline__ void split34pk(float4 v, uint2& h, uint2& m, uint2& lo) {
  split3pk(v.x, v.y, h.x, m.x, lo.x);
  split3pk(v.z, v.w, h.y, m.y, lo.y);
}

// ---------- device-wide spin barrier (all blocks co-resident: grid 384 << capacity) ----------
static __device__ __forceinline__ void gbar(int* ctr, int nb) {
  __threadfence();          // release: make this block's stores visible device-wide
  __syncthreads();
  if (threadIdx.x == 0) {
    atomicAdd(ctr, 1);
    while (atomicAdd(ctr, 0) < nb) __builtin_amdgcn_s_sleep(4);
  }
  __syncthreads();
  __threadfence();          // acquire
}

// ---------- setup: zero deg/hists/replicas/candcnt/barriers + dtype detect (merged) ----------
__global__ void zero_detect_kernel(int* __restrict__ degcur, unsigned* __restrict__ hists,
                                   unsigned* __restrict__ rep, int* __restrict__ candcnt4,
                                   int* __restrict__ bar, int N, const void* __restrict__ ei,
                                   int* __restrict__ flag, int E) {
  int i = blockIdx.x * blockDim.x + threadIdx.x;
  if (i < N) degcur[i] = 0;
  if (i < 4096) hists[i] = 0u;
  if (i < 32768) rep[i] = 0u;
  if (i < 4) candcnt4[i] = 0;
  if (i < 16) bar[i] = 0;
  const int* p = (const int*)ei;
  int lim = (E < 65536) ? E : 65536;
  int any = 0;
  for (int j = i; j < lim; j += gridDim.x * blockDim.x) any |= (p[2 * j + 1] != 0);
  if (__any(any))
    if ((threadIdx.x & 63) == 0 && any) atomicOr(flag, 1);
}

// ---------- cvt + degree count ----------
__global__ void cvt_deg_kernel(const void* __restrict__ ei, const int* __restrict__ flag,
                               int* __restrict__ src, int* __restrict__ dst,
                               int* __restrict__ degcur, int E) {
  int i = blockIdx.x * blockDim.x + threadIdx.x;
  if (i >= E) return;
  int s, d;
  if (*flag) { const int* p = (const int*)ei; s = p[i]; d = p[E + i]; }
  else { const long long* p = (const long long*)ei; s = (int)p[i]; d = (int)p[(size_t)E + i]; }
  src[i] = s;
  dst[i] = d;
  atomicAdd(&degcur[s], 1);
}

// ---------- rowptr scan (also leaves cursor copy in degcur) ----------
__global__ void scan_rowptr_kernel(int* __restrict__ degcur, int* __restrict__ rowptr, int N) {
  const int tid = threadIdx.x;  // 1024
  const int lane = tid & 63, wid = tid >> 6;
  __shared__ int wsumS[16];
  __shared__ int sbase;
  if (tid == 0) sbase = 0;
  __syncthreads();
  for (int base = 0; base < N; base += 1024) {
    int i = base + tid;
    int v = (i < N) ? degcur[i] : 0;
    int x = v;
#pragma unroll
    for (int off = 1; off < 64; off <<= 1) {
      int y = __shfl_up(x, off, 64);
      if (lane >= off) x += y;
    }
    if (lane == 63) wsumS[wid] = x;
    __syncthreads();
    int wbase = 0;
#pragma unroll
    for (int w2 = 0; w2 < 16; ++w2) wbase += (w2 < wid) ? wsumS[w2] : 0;
    int excl = sbase + wbase + x - v;
    if (i < N) { rowptr[i] = excl; degcur[i] = excl; }
    __syncthreads();
    if (tid == 1023) sbase += wbase + x;
    __syncthreads();
  }
  if (tid == 0) rowptr[N] = sbase;
}

__global__ void scatter_kernel(const int* __restrict__ src, int* __restrict__ cursor,
                               int* __restrict__ eids, int E) {
  int e = blockIdx.x * blockDim.x + threadIdx.x;
  if (e >= E) return;
  int p = atomicAdd(&cursor[src[e]], 1);
  eids[p] = e;
}

// ---------- determinism: sort each segment's edge ids ascending (thread/node) ----------
__global__ void sort_eids_kernel(const int* __restrict__ rowptr, int* __restrict__ eids, int N) {
  int n = blockIdx.x * blockDim.x + threadIdx.x;
  if (n >= N) return;
  int p0 = rowptr[n], p1 = rowptr[n + 1];
  for (int i = p0 + 1; i < p1; ++i) {
    int key = eids[i];
    int j = i - 1;
    while (j >= p0 && eids[j] > key) { eids[j + 1] = eids[j]; --j; }
    eids[j + 1] = key;
  }
}

// ---------- merged: wa_all (blocks 0..3) + weight pre-split/tile with mu perm (blocks 4..55) ----
// RUNTIME k-map calibration: 32 exact-integer MFMA probes measure mu(t) = hA^-1(hB(t)).
// Storing B slot t <- B[k=mu(t)] equalizes the effective k-permutations for ANY hA,hB.
__global__ void wprep_kernel(const float* __restrict__ W, const float* __restrict__ a,
                             float* __restrict__ wa_all, const float* __restrict__ xw,
                             u16* __restrict__ wtH, u16* __restrict__ wtM,
                             u16* __restrict__ wtL) {
  int blk = blockIdx.x;  // 0..55
  int tid = threadIdx.x; // 384
  if (blk < 4) {
    int it = blk, k = tid;
    const float* row = W + ((size_t)it * 384 + k) * DOUT;
    const float* ai = a + (size_t)it * DOUT;
    float acc = 0.f;
    for (int j = 0; j < DOUT; ++j) acc = fmaf(row[j], ai[j], acc);
    wa_all[it * 384 + k] = acc;
    return;
  }
  __shared__ int muS[32];
  {
    int lw = tid & 63, g = lw >> 4;
    bf16x8 aEnc;
#pragma unroll
    for (int j = 0; j < 8; ++j) aEnc[j] = bf16i(8 * g + j + 1);   // A-slot index encode
    f32x4 z = {0.f, 0.f, 0.f, 0.f};
    for (int t0 = 0; t0 < 32; ++t0) {
      int g0 = t0 >> 3, j0 = t0 & 7;
      bf16x8 bOne;
#pragma unroll
      for (int j = 0; j < 8; ++j)
        bOne[j] = (g == g0 && j == j0) ? (short)0x3F80 : (short)0;  // one-hot B slot t0
      f32x4 d = mfma16x16x32(aEnc, bOne, z);
      if (tid == t0) muS[t0] = ((int)(d[0] + 0.5f) - 1) & 31;
    }
  }
  __syncthreads();
  int b = blk - 4;  // 0..51
  int set, ks;
  const float* srcp;
  if (b < 4) { set = 0; ks = b; srcp = xw; }
  else { set = 1 + (b - 4) / 12; ks = (b - 4) % 12; srcp = W + (size_t)(set - 1) * 384 * DOUT; }
  size_t base = ((size_t)set * 12 + ks) * 4096;
  for (int i = tid; i < 4096; i += blockDim.x) {
    int col = i >> 5, t = i & 31;
    float x = srcp[(size_t)(ks * 32 + muS[t]) * DOUT + col];   // k pre-permuted by mu
    u16 h, m, l;
    split3(x, h, m, l);
    wtH[base + i] = h;
    wtM[base + i] = m;
    wtL[base + i] = l;
  }
}

// ---------- et4[it][e] = ete[e]·wa3(it), planar output ----------
__global__ __launch_bounds__(256) void et4_kernel(const float* __restrict__ ete,
                                                  const float* __restrict__ wa_all,
                                                  float* __restrict__ et4, int E) {
  __shared__ float4 w3s[4][32];
  int tid = threadIdx.x;
  if (tid < 128) {
    int it = tid >> 5, k4 = tid & 31;
    const float* base = wa_all + it * 384 + 256 + k4 * 4;
    w3s[it][k4] = make_float4(base[0], base[1], base[2], base[3]);
  }
  __syncthreads();
  int e = blockIdx.x * blockDim.x + tid;
  if (e >= E) return;
  const float4* row = (const float4*)(ete + (size_t)e * DOUT);
  float a0 = 0.f, a1 = 0.f, a2 = 0.f, a3 = 0.f;
#pragma unroll
  for (int k4 = 0; k4 < 32; ++k4) {
    float4 r = row[k4];
    float4 w0 = w3s[0][k4], w1 = w3s[1][k4], w2 = w3s[2][k4], w3v = w3s[3][k4];
    a0 = fmaf(r.x, w0.x, fmaf(r.y, w0.y, fmaf(r.z, w0.z, fmaf(r.w, w0.w, a0))));
    a1 = fmaf(r.x, w1.x, fmaf(r.y, w1.y, fmaf(r.z, w1.z, fmaf(r.w, w1.w, a1))));
    a2 = fmaf(r.x, w2.x, fmaf(r.y, w2.y, fmaf(r.z, w2.z, fmaf(r.w, w2.w, a2))));
    a3 = fmaf(r.x, w3v.x, fmaf(r.y, w3v.y, fmaf(r.z, w3v.z, fmaf(r.w, w3v.w, a3))));
  }
  et4[e] = a0;
  et4[(size_t)E + e] = a1;
  et4[(size_t)2 * E + e] = a2;
  et4[(size_t)3 * E + e] = a3;
}

// ---------- fused score + segment softmax + REPLICATED hist level 0 ----------
__global__ __launch_bounds__(256) void softmax_kernel(
    const int* __restrict__ rowptr, const int* __restrict__ eids, const int* __restrict__ dst,
    const float* __restrict__ pa, const float* __restrict__ qa, const float* __restrict__ et4,
    int it, int E, float* __restrict__ alpha, unsigned* __restrict__ rep0, int N) {
  __shared__ unsigned lh[256];
  int tid = threadIdx.x;
  lh[tid] = 0u;
  __syncthreads();
  const float* etp = et4 + (size_t)it * E;
  int w = (int)(((size_t)blockIdx.x * blockDim.x + tid) >> 6);
  int lane = tid & 63;
  if (w < N) {
    int p0 = rowptr[w], p1 = rowptr[w + 1];
    int deg = p1 - p0;
    if (deg > 0) {
      float pan = pa[w];
      if (deg <= 64) {
        int p = p0 + lane;
        int e = -1;
        float sv = -3.402823466e38f;
        if (p < p1) {
          e = eids[p];
          float s = pan + qa[dst[e]] + etp[e];
          sv = (s >= 0.f) ? s : 0.2f * s;
        }
        float m = wmax64(sv);
        float ee = (e >= 0) ? expf(sv - m) : 0.f;
        float den = 0.f;
        for (int i = 0; i < deg; ++i) den += __shfl(ee, i, 64);  // ordered sum
        den += 1e-16f;
        if (e >= 0) {
          float av = ee / den;
          alpha[e] = av;
          atomicAdd(&lh[__float_as_uint(av) >> 24], 1u);
        }
      } else if (deg <= 256) {
        float sv[4]; int ev[4];
#pragma unroll
        for (int u = 0; u < 4; ++u) {
          int p = p0 + u * 64 + lane;
          if (p < p1) {
            int e = eids[p];
            ev[u] = e;
            float s = pan + qa[dst[e]] + etp[e];
            sv[u] = (s >= 0.f) ? s : 0.2f * s;
          } else { ev[u] = -1; sv[u] = -3.402823466e38f; }
        }
        float m = fmaxf(fmaxf(sv[0], sv[1]), fmaxf(sv[2], sv[3]));
        m = wmax64(m);
        float ssum = 0.f;
#pragma unroll
        for (int u = 0; u < 4; ++u)
          if (ev[u] >= 0) { sv[u] = expf(sv[u] - m); ssum += sv[u]; }
        ssum = wsum64(ssum);
        float den = ssum + 1e-16f;
#pragma unroll
        for (int u = 0; u < 4; ++u)
          if (ev[u] >= 0) {
            float av = sv[u] / den;
            alpha[ev[u]] = av;
            atomicAdd(&lh[__float_as_uint(av) >> 24], 1u);
          }
      } else {
        float m = -3.402823466e38f;
        for (int p = p0 + lane; p < p1; p += 64) {
          int e = eids[p];
          float s = pan + qa[dst[e]] + etp[e];
          s = (s >= 0.f) ? s : 0.2f * s;
          m = fmaxf(m, s);
        }
        m = wmax64(m);
        float ssum = 0.f;
        for (int p = p0 + lane; p < p1; p += 64) {
          int e = eids[p];
          float s = pan + qa[dst[e]] + etp[e];
          s = (s >= 0.f) ? s : 0.2f * s;
          ssum += expf(s - m);
        }
        ssum = wsum64(ssum);
        float den = ssum + 1e-16f;
        for (int p = p0 + lane; p < p1; p += 64) {
          int e = eids[p];
          float s = pan + qa[dst[e]] + etp[e];
          s = (s >= 0.f) ? s : 0.2f * s;
          float av = expf(s - m) / den;
          alpha[e] = av;
          atomicAdd(&lh[__float_as_uint(av) >> 24], 1u);
        }
      }
    }
  }
  __syncthreads();
  if (lh[tid]) atomicAdd(&rep0[(blockIdx.x & 31) * 256 + tid], lh[tid]);
}

// ---------- MERGED radix-select: levels 1..3 + resolve in ONE persistent kernel ----------
// 384 blocks x 256 threads (co-resident: 1536 waves << 8192 capacity) with device spin
// barriers.  Selection algebra identical to the old hist1/hist/hist3c/resolve24 chain.
// Post-barrier histogram reads use atomic-loads (device-coherent across XCDs).
__device__ __forceinline__ void scan256g(unsigned* __restrict__ hist, unsigned krem_in,
                                         unsigned* lds, unsigned* res,
                                         unsigned& bin, unsigned& krem_out) {
  int t = threadIdx.x;
  lds[t] = atomicAdd(&hist[t], 0u);   // coherent read
  __syncthreads();
  for (int off = 1; off < 256; off <<= 1) {
    unsigned add = (t + off < 256) ? lds[t + off] : 0u;
    __syncthreads();
    lds[t] += add;
    __syncthreads();
  }
  if (t < 256) {
    unsigned above = (t == 255) ? 0u : lds[t + 1];
    if (lds[t] >= krem_in && above < krem_in) { res[0] = (unsigned)t; res[1] = krem_in - above; }
  }
  __syncthreads();
  bin = res[0];
  krem_out = res[1];
  __syncthreads();
}

__global__ __launch_bounds__(256) void select_kernel(
    const float* __restrict__ alpha, const unsigned* __restrict__ rep0,
    unsigned* __restrict__ hists_it, unsigned Ktop,
    int* __restrict__ candList, int* __restrict__ candCnt,
    int* __restrict__ header, float* __restrict__ amask, int E, int* __restrict__ bar) {
  __shared__ unsigned lds[256], res2[2], lh[256];
  __shared__ int tiel[4096];
  __shared__ int tiec;
  const int t = threadIdx.x;
  const int nb = (int)gridDim.x;
  const int stride = nb * 256;
  // ---- level 0 scan from replicas (per-block redundant, no stream) ----
  unsigned v = 0u;
#pragma unroll
  for (int r = 0; r < 32; ++r) v += rep0[r * 256 + t];
  lds[t] = v;
  __syncthreads();
  for (int off = 1; off < 256; off <<= 1) {
    unsigned add = (t + off < 256) ? lds[t + off] : 0u;
    __syncthreads();
    lds[t] += add;
    __syncthreads();
  }
  {
    unsigned above = (t == 255) ? 0u : lds[t + 1];
    if (lds[t] >= Ktop && above < Ktop) { res2[0] = (unsigned)t; res2[1] = Ktop - above; }
  }
  __syncthreads();
  unsigned bin0 = res2[0], krem = res2[1];
  __syncthreads();
  // ---- build level-1 ----
  lh[t] = 0u;
  __syncthreads();
  for (int e = blockIdx.x * 256 + t; e < E; e += stride) {
    unsigned b = __float_as_uint(alpha[e]);
    if ((b >> 24) == bin0) atomicAdd(&lh[(b >> 16) & 0xFFu], 1u);
  }
  __syncthreads();
  if (lh[t]) atomicAdd(&hists_it[256 + t], lh[t]);
  gbar(bar + 0, nb);
  // ---- scan level-1; build level-2 ----
  unsigned bin1, k2;
  scan256g(hists_it + 256, krem, lds, res2, bin1, k2);
  krem = k2;
  unsigned pref16 = (bin0 << 8) | bin1;
  lh[t] = 0u;
  __syncthreads();
  for (int e = blockIdx.x * 256 + t; e < E; e += stride) {
    unsigned b = __float_as_uint(alpha[e]);
    if ((b >> 16) == pref16) atomicAdd(&lh[(b >> 8) & 0xFFu], 1u);
  }
  __syncthreads();
  if (lh[t]) atomicAdd(&hists_it[512 + t], lh[t]);
  gbar(bar + 1, nb);
  // ---- scan level-2; build level-3 + collect candidates ----
  unsigned bin2;
  scan256g(hists_it + 512, krem, lds, res2, bin2, k2);
  krem = k2;
  unsigned pref24 = (pref16 << 8) | bin2;
  lh[t] = 0u;
  __syncthreads();
  for (int e = blockIdx.x * 256 + t; e < E; e += stride) {
    unsigned b = __float_as_uint(alpha[e]);
    if ((b >> 8) == pref24) {
      atomicAdd(&lh[b & 0xFFu], 1u);
      int p = atomicAdd(candCnt, 1);
      if (p < 4096) candList[p] = e;
    }
  }
  __syncthreads();
  if (lh[t]) atomicAdd(&hists_it[768 + t], lh[t]);
  // ---- arrive; only block 0 resolves ----
  __threadfence();
  __syncthreads();
  if (t == 0) atomicAdd(bar + 2, 1);
  if (blockIdx.x != 0) return;
  if (t == 0) {
    while (atomicAdd(bar + 2, 0) < nb) __builtin_amdgcn_s_sleep(4);
  }
  __syncthreads();
  __threadfence();
  // ---- scan level-3 -> thr bits + need count ----
  unsigned bin3, needU;
  scan256g(hists_it + 768, krem, lds, res2, bin3, needU);
  unsigned thr = (pref24 << 8) | bin3;
  int needT = (int)needU;
  int cc = atomicAdd(candCnt, 0);
  if (t == 0) tiec = 0;
  __syncthreads();
  if (cc <= 4096) {
    for (int i = t; i < cc; i += blockDim.x) {
      int e = candList[i];
      if (__float_as_uint(alpha[e]) == thr) { int p = atomicAdd(&tiec, 1); tiel[p] = e; }
    }
    __syncthreads();
    int ce = tiec;
    int dropc = ce - needT;
    if (dropc <= 0) {
      if (t == 0) { header[0] = 0; header[1] = (int)thr; header[2] = 0; }
      return;
    }
    if (dropc <= 64) {
      int sortN = 64;
      while (sortN < ce) sortN <<= 1;
      for (int i = t; i < sortN; i += blockDim.x)
        if (i >= ce) tiel[i] = 0x7fffffff;
      __syncthreads();
      for (int k = 2; k <= sortN; k <<= 1) {
        for (int j = k >> 1; j > 0; j >>= 1) {
          for (int i = t; i < sortN; i += blockDim.x) {
            int ixj = i ^ j;
            if (ixj > i) {
              int v0 = tiel[i], v1 = tiel[ixj];
              bool up = ((i & k) == 0);
              if ((v0 > v1) == up) { tiel[i] = v1; tiel[ixj] = v0; }
            }
          }
          __syncthreads();
        }
      }
      if (t == 0) { header[0] = 0; header[1] = (int)thr; header[2] = dropc; }
      for (int i = t; i < dropc; i += blockDim.x) header[3 + i] = tiel[needT + i];
      return;
    }
  }
  // adversarial fallback: write FULL amask deterministically (256 threads; slow but correct)
  if (t == 0) header[0] = 1;
  __shared__ int wtot4[4];
  __shared__ int sbase;
  if (t == 0) sbase = 0;
  __syncthreads();
  int lane = t & 63, wid = t >> 6;
  for (int base = 0; base < E; base += 256) {
    int e = base + t;
    float a = 0.f; int f = 0; unsigned b = 0u;
    if (e < E) { a = alpha[e]; b = __float_as_uint(a); f = (b == thr) ? 1 : 0; }
    int x = f;
#pragma unroll
    for (int off = 1; off < 64; off <<= 1) {
      int y = __shfl_up(x, off, 64);
      if (lane >= off) x += y;
    }
    if (lane == 63) wtot4[wid] = x;
    __syncthreads();
    int wbase = 0;
#pragma unroll
    for (int w2 = 0; w2 < 4; ++w2) wbase += (w2 < wid) ? wtot4[w2] : 0;
    if (e < E) {
      float outv = 0.f;
      if (b > thr) outv = a;
      else if (f && (sbase + wbase + x - f) < needT) outv = a;
      amask[e] = outv;
    }
    __syncthreads();
    if (t == 255) sbase += wbase + x;
    __syncthreads();
  }
}

// ---------- per-edge weight: threshold alpha inline (flag=1 -> amask fallback) ----------
static __device__ __forceinline__ float edge_w(const float* __restrict__ alpha,
                                               const float* __restrict__ amask,
                                               const int* __restrict__ hdr, int flg,
                                               unsigned thr, int dc, int e) {
  if (flg) return amask[e];
  float av = alpha[e];
  unsigned b = __float_as_uint(av);
  if (b > thr) return av;
  if (b == thr) {
    for (int j = 0; j < dc; ++j)
      if (hdr[3 + j] == e) return 0.f;
    return av;
  }
  return 0.f;
}

// ---------- aggregation (wave per node, split halves, metadata prefetch) ----------
__global__ void agg_kernel(const int* __restrict__ rowptr, const int* __restrict__ eids,
                           const int* __restrict__ dst, const float* __restrict__ alpha,
                           const float* __restrict__ amask, const int* __restrict__ hdr,
                           const float* __restrict__ xc, const float* __restrict__ ete,
                           float* __restrict__ sa, float* __restrict__ vbuf,
                           float* __restrict__ tbuf, int N) {
  int w = (int)(((size_t)blockIdx.x * blockDim.x + threadIdx.x) >> 6);
  int lane = threadIdx.x & 63;
  if (w >= N) return;
  const int flg = hdr[0];
  const unsigned thr = (unsigned)hdr[1];
  const int dc = hdr[2];
  int p0 = rowptr[w], p1 = rowptr[w + 1];
  int deg = p1 - p0;
  const int half = lane >> 5;
  const int l32 = lane & 31;
  const float4* xc4 = (const float4*)xc;
  const float4* et4p = (const float4*)ete;
  float4 acc = make_float4(0.f, 0.f, 0.f, 0.f);
  float s = 0.f;
  if (deg <= 64) {
    int p = p0 + lane;
    int e = -1; float am = 0.f; int dd = 0;
    if (p < p1) { e = eids[p]; am = edge_w(alpha, amask, hdr, flg, thr, dc, e); dd = dst[e]; }
    for (int i = 0; i < deg; ++i) {
      float a = __shfl(am, i, 64);
      if (a != 0.f) {
        int ei = __shfl(e, i, 64);
        int di = __shfl(dd, i, 64);
        const float4* b = half ? (et4p + (size_t)ei * 32) : (xc4 + (size_t)di * 32);
        float4 r = b[l32];
        acc.x = fmaf(a, r.x, acc.x); acc.y = fmaf(a, r.y, acc.y);
        acc.z = fmaf(a, r.z, acc.z); acc.w = fmaf(a, r.w, acc.w);
        s += a;
      }
    }
  } else {
    for (int p = p0; p < p1; ++p) {
      int e0 = eids[p];
      float a0 = edge_w(alpha, amask, hdr, flg, thr, dc, e0);
      if (a0 != 0.f) {
        int d0 = dst[e0];
        const float4* b0 = half ? (et4p + (size_t)e0 * 32) : (xc4 + (size_t)d0 * 32);
        float4 r = b0[l32];
        acc.x = fmaf(a0, r.x, acc.x); acc.y = fmaf(a0, r.y, acc.y);
        acc.z = fmaf(a0, r.z, acc.z); acc.w = fmaf(a0, r.w, acc.w);
        s += a0;
      }
    }
  }
  if (half == 0) ((float4*)vbuf)[(size_t)w * 32 + l32] = acc;
  else           ((float4*)tbuf)[(size_t)w * 32 + l32] = acc;
  if (lane == 0) sa[w] = s;
}

// ---------- MFMA GEMM: C[Nx128] = concat(sca*A0|A1|A2)[N x 128*nseg] @ B (+bias)
// fp32 emulated via 3-way RNE bf16 split (6 product terms, residual ~2^-24 rel).
// SELF-CALIBRATING on all lane maps (k-maps via mu-permuted B; C/D via in-kernel probes
// + measured-map LDS slab epilogue).  cvt_pk hot split + 1-step register prefetch.
//            epi=1: fused pa/qa for next iter;  epi=2: fused ELU+LayerNorm -> outp ----------
__global__ __launch_bounds__(256) void gemm_mfma_kernel(
    const float* __restrict__ A0, const float* __restrict__ A1, const float* __restrict__ A2,
    const float* __restrict__ sca, const u16* __restrict__ wtH, const u16* __restrict__ wtM,
    const u16* __restrict__ wtL, const float* __restrict__ bias, float* __restrict__ C,
    int N, int nseg,
    const float* __restrict__ wa_next, float* __restrict__ pa, float* __restrict__ qa,
    const float* __restrict__ gamma, const float* __restrict__ beta,
    float* __restrict__ outp, int epi) {
  __shared__ __align__(16) char smem[61440];
  u16 (*AsH)[40] = (u16(*)[40])(smem);
  u16 (*AsM)[40] = (u16(*)[40])(smem + 10240);
  u16 (*AsL)[40] = (u16(*)[40])(smem + 20480);
  u16 (*BsH)[40] = (u16(*)[40])(smem + 30720);
  u16 (*BsM)[40] = (u16(*)[40])(smem + 40960);
  u16 (*BsL)[40] = (u16(*)[40])(smem + 51200);
  const int tid = threadIdx.x;
  const int m0 = blockIdx.x * 128;
  const int K = DOUT * nseg;
  const int w = tid >> 6, l = tid & 63;
  const int cb = l & 15, g = l >> 4;

  // --- C/D lane-map calibration (2 exact-integer MFMAs) ---
  int rowlab[4], collab[4];
  {
    bf16x8 enc, ones;
#pragma unroll
    for (int j = 0; j < 8; ++j) { enc[j] = bf16i(cb + 1); ones[j] = (short)0x3F80; }
    f32x4 z = {0.f, 0.f, 0.f, 0.f};
    f32x4 dR = mfma16x16x32(enc, ones, z);   // D = 32*(row+1)
    f32x4 dC = mfma16x16x32(ones, enc, z);   // D = 32*(col+1)
#pragma unroll
    for (int r = 0; r < 4; ++r) {
      rowlab[r] = ((int)(dR[r] * (1.f / 32.f) + 0.5f) - 1) & 15;
      collab[r] = ((int)(dC[r] * (1.f / 32.f) + 0.5f) - 1) & 15;
    }
  }

  f32x4 acc[2][8];
#pragma unroll
  for (int i = 0; i < 2; ++i)
#pragma unroll
    for (int j = 0; j < 8; ++j) acc[i][j] = (f32x4){0.f, 0.f, 0.f, 0.f};

  // staging role: thread handles A row (tid>>1), 16 floats at col half*16
  const int srow = tid >> 1, shalf = tid & 1;
  const int grow_s = m0 + srow;
  float scv = 1.f;
  if (sca && grow_s < N) scv = sca[grow_s];

  auto loadA = [&](int kc, float4& v0, float4& v1, float4& v2, float4& v3) {
    const int seg = kc >> 7;
    const float* Ap = (seg == 0) ? A0 : (seg == 1) ? A1 : A2;
    v0 = make_float4(0.f, 0.f, 0.f, 0.f); v1 = v0; v2 = v0; v3 = v0;
    if (grow_s < N) {
      const float4* p = (const float4*)(Ap + (size_t)grow_s * DOUT + (kc & 127) + shalf * 16);
      v0 = p[0]; v1 = p[1]; v2 = p[2]; v3 = p[3];
      if (seg == 0 && sca) {
        v0.x *= scv; v0.y *= scv; v0.z *= scv; v0.w *= scv;
        v1.x *= scv; v1.y *= scv; v1.z *= scv; v1.w *= scv;
        v2.x *= scv; v2.y *= scv; v2.z *= scv; v2.w *= scv;
        v3.x *= scv; v3.y *= scv; v3.z *= scv; v3.w *= scv;
      }
    }
  };
  auto loadB = [&](int kc, uint4& h0, uint4& h1, uint4& m0u, uint4& m1u, uint4& l0u,
                   uint4& l1u) {
    size_t sb = (size_t)(kc >> 5) << 12;
    const uint4* gh = (const uint4*)(wtH + sb) + tid * 2;
    const uint4* gm = (const uint4*)(wtM + sb) + tid * 2;
    const uint4* gl = (const uint4*)(wtL + sb) + tid * 2;
    h0 = gh[0]; h1 = gh[1];
    m0u = gm[0]; m1u = gm[1];
    l0u = gl[0]; l1u = gl[1];
  };

  float4 av0, av1, av2, av3, nv0, nv1, nv2, nv3;
  uint4 bh0, bh1, bm0u, bm1u, bl0u, bl1u, nh0, nh1, nm0, nm1, nl0, nl1;
  loadA(0, av0, av1, av2, av3);
  loadB(0, bh0, bh1, bm0u, bm1u, bl0u, bl1u);

  const int nks = K >> 5;
  for (int ks = 0; ks < nks; ++ks) {
    const int kc = ks << 5;
    {
      uint2 h0, m0v, l0, h1, m1v, l1, h2, m2v, l2, h3, m3v, l3;
      split34pk(av0, h0, m0v, l0); split34pk(av1, h1, m1v, l1);
      split34pk(av2, h2, m2v, l2); split34pk(av3, h3, m3v, l3);
      *(uint4*)&AsH[srow][shalf * 16]     = make_uint4(h0.x, h0.y, h1.x, h1.y);
      *(uint4*)&AsH[srow][shalf * 16 + 8] = make_uint4(h2.x, h2.y, h3.x, h3.y);
      *(uint4*)&AsM[srow][shalf * 16]     = make_uint4(m0v.x, m0v.y, m1v.x, m1v.y);
      *(uint4*)&AsM[srow][shalf * 16 + 8] = make_uint4(m2v.x, m2v.y, m3v.x, m3v.y);
      *(uint4*)&AsL[srow][shalf * 16]     = make_uint4(l0.x, l0.y, l1.x, l1.y);
      *(uint4*)&AsL[srow][shalf * 16 + 8] = make_uint4(l2.x, l2.y, l3.x, l3.y);
      *(uint4*)&BsH[srow][shalf * 16]     = bh0;
      *(uint4*)&BsH[srow][shalf * 16 + 8] = bh1;
      *(uint4*)&BsM[srow][shalf * 16]     = bm0u;
      *(uint4*)&BsM[srow][shalf * 16 + 8] = bm1u;
      *(uint4*)&BsL[srow][shalf * 16]     = bl0u;
      *(uint4*)&BsL[srow][shalf * 16 + 8] = bl1u;
    }
    if (ks + 1 < nks) {
      loadA(kc + 32, nv0, nv1, nv2, nv3);
      loadB(kc + 32, nh0, nh1, nm0, nm1, nl0, nl1);
    }
    __syncthreads();
    bf16x8 aH0 = *(const bf16x8*)&AsH[w * 32 + cb][g * 8];
    bf16x8 aH1 = *(const bf16x8*)&AsH[w * 32 + 16 + cb][g * 8];
    bf16x8 aM0 = *(const bf16x8*)&AsM[w * 32 + cb][g * 8];
    bf16x8 aM1 = *(const bf16x8*)&AsM[w * 32 + 16 + cb][g * 8];
    bf16x8 aL0 = *(const bf16x8*)&AsL[w * 32 + cb][g * 8];
    bf16x8 aL1 = *(const bf16x8*)&AsL[w * 32 + 16 + cb][g * 8];
#pragma unroll
    for (int ct = 0; ct < 8; ++ct) {
      bf16x8 bH = *(const bf16x8*)&BsH[ct * 16 + cb][g * 8];
      bf16x8 bM = *(const bf16x8*)&BsM[ct * 16 + cb][g * 8];
      bf16x8 bL = *(const bf16x8*)&BsL[ct * 16 + cb][g * 8];
      acc[0][ct] = mfma16x16x32(aH0, bH, acc[0][ct]);
      acc[1][ct] = mfma16x16x32(aH1, bH, acc[1][ct]);
      acc[0][ct] = mfma16x16x32(aM0, bH, acc[0][ct]);
      acc[1][ct] = mfma16x16x32(aM1, bH, acc[1][ct]);
      acc[0][ct] = mfma16x16x32(aL0, bH, acc[0][ct]);
      acc[1][ct] = mfma16x16x32(aL1, bH, acc[1][ct]);
      acc[0][ct] = mfma16x16x32(aH0, bM, acc[0][ct]);
      acc[1][ct] = mfma16x16x32(aH1, bM, acc[1][ct]);
      acc[0][ct] = mfma16x16x32(aM0, bM, acc[0][ct]);
      acc[1][ct] = mfma16x16x32(aM1, bM, acc[1][ct]);
      acc[0][ct] = mfma16x16x32(aH0, bL, acc[0][ct]);
      acc[1][ct] = mfma16x16x32(aH1, bL, acc[1][ct]);
    }
    __syncthreads();
    av0 = nv0; av1 = nv1; av2 = nv2; av3 = nv3;
    bh0 = nh0; bh1 = nh1; bm0u = nm0; bm1u = nm1; bl0u = nl0; bl1u = nl1;
  }

  // ---- epilogue: measured-map scatter into per-wave LDS slab, canonical read-back ----
  float* slab = (float*)(smem + (size_t)w * 8448);  // [16][132] f32
  const int row16 = l & 15;
  const int csel = (l >> 4) * 32;
#pragma unroll
  for (int rt = 0; rt < 2; ++rt) {
#pragma unroll
    for (int ct = 0; ct < 8; ++ct)
#pragma unroll
      for (int r = 0; r < 4; ++r)
        slab[rowlab[r] * 132 + ct * 16 + collab[r]] = acc[rt][ct][r];
    __syncthreads();
    int grow = m0 + w * 32 + rt * 16 + row16;
    float v[32];
#pragma unroll
    for (int q = 0; q < 8; ++q) {
      float4 t4 = *(float4*)&slab[row16 * 132 + csel + q * 4];
      v[q * 4 + 0] = t4.x; v[q * 4 + 1] = t4.y; v[q * 4 + 2] = t4.z; v[q * 4 + 3] = t4.w;
    }
    if (bias) {
#pragma unroll
      for (int q = 0; q < 8; ++q) {
        float4 bb = *(const float4*)(bias + csel + q * 4);
        v[q * 4 + 0] += bb.x; v[q * 4 + 1] += bb.y; v[q * 4 + 2] += bb.z; v[q * 4 + 3] += bb.w;
      }
    }
    if (epi == 2) {  // ELU + LayerNorm -> outp
#pragma unroll
      for (int i = 0; i < 32; ++i) v[i] = (v[i] > 0.f) ? v[i] : expm1f(v[i]);
      float s = 0.f;
#pragma unroll
      for (int i = 0; i < 32; ++i) s += v[i];
      s = rsumg(s);
      float mu = s * (1.f / 128.f);
      float sq = 0.f;
#pragma unroll
      for (int i = 0; i < 32; ++i) { float d = v[i] - mu; sq += d * d; }
      sq = rsumg(sq);
      float rstd = rsqrtf(sq * (1.f / 128.f) + 1e-5f);
      if (grow < N) {
#pragma unroll
        for (int q = 0; q < 8; ++q) {
          float4 ga = *(const float4*)(gamma + csel + q * 4);
          float4 be = *(const float4*)(beta + csel + q * 4);
          float4 o;
          o.x = (v[q * 4 + 0] - mu) * rstd * ga.x + be.x;
          o.y = (v[q * 4 + 1] - mu) * rstd * ga.y + be.y;
          o.z = (v[q * 4 + 2] - mu) * rstd * ga.z + be.z;
          o.w = (v[q * 4 + 3] - mu) * rstd * ga.w + be.w;
          *(float4*)(outp + (size_t)grow * DOUT + csel + q * 4) = o;
        }
      }
    } else {
      if (grow < N) {
#pragma unroll
        for (int q = 0; q < 8; ++q)
          *(float4*)(C + (size_t)grow * DOUT + csel + q * 4) =
              make_float4(v[q * 4 + 0], v[q * 4 + 1], v[q * 4 + 2], v[q * 4 + 3]);
      }
      if (epi == 1) {  // pa/qa for next iteration's scores
        float pp = 0.f, qq = 0.f;
#pragma unroll
        for (int i = 0; i < 32; ++i) {
          pp = fmaf(v[i], wa_next[csel + i], pp);
          qq = fmaf(v[i], wa_next[128 + csel + i], qq);
        }
        pp = rsumg(pp);
        qq = rsumg(qq);
        if ((l >> 4) == 0 && grow < N) { pa[grow] = pp; qa[grow] = qq; }
      }
    }
    __syncthreads();
  }
}

extern "C" void kernel_launch(void* const* d_in, const int* in_sizes, int n_in,
                              void* d_out, int out_size, void* d_ws, size_t ws_size,
                              hipStream_t stream) {
  const int E = in_sizes[0] / 2;
  const int N = in_sizes[1] / DOUT;
  const unsigned Ktop = (unsigned)(E / 2);  // int(E * 0.5)

  const void*  ei    = d_in[0];
  const float* x     = (const float*)d_in[1];
  const float* ete   = (const float*)d_in[2];
  const float* W     = (const float*)d_in[3];
  const float* a     = (const float*)d_in[4];
  const float* xw    = (const float*)d_in[5];
  const float* xb    = (const float*)d_in[6];
  const float* gamma = (const float*)d_in[7];
  const float* beta  = (const float*)d_in[8];
  float* out = (float*)d_out;

  size_t off = 0;
  auto take = [&](size_t bytes) -> char* {
    char* p = (char*)d_ws + off;
    off += (bytes + 255) & ~(size_t)255;
    return p;
  };
  int*      src32   = (int*)take((size_t)E * 4);
  int*      dst32   = (int*)take((size_t)E * 4);
  int*      rowptr  = (int*)take(((size_t)N + 1) * 4);
  int*      degcur  = (int*)take((size_t)N * 4);
  int*      eids    = (int*)take((size_t)E * 4);
  float*    pa      = (float*)take((size_t)N * 4);
  float*    qa      = (float*)take((size_t)N * 4);
  float*    wa_all  = (float*)take(4 * 384 * 4);
  float*    alpha   = (float*)take((size_t)E * 4);
  float*    amask   = (float*)take((size_t)E * 4);
  float*    sa      = (float*)take((size_t)N * 4);
  float*    vbuf    = (float*)take((size_t)N * DOUT * 4);
  float*    tbuf    = (float*)take((size_t)N * DOUT * 4);
  float*    xcA     = (float*)take((size_t)N * DOUT * 4);
  float*    xcB     = (float*)take((size_t)N * DOUT * 4);
  float*    et4     = (float*)take((size_t)E * 4 * 4);
  unsigned* hists   = (unsigned*)take(4 * 4 * 256 * 4);   // [it][level][256]
  unsigned* rep     = (unsigned*)take(4 * 32 * 256 * 4);  // [it][replica][256]
  int*      candcnt4= (int*)take(64);
  int*      flag    = (int*)take(64);
  int*      candList= (int*)take(4096 * 4);
  int*      header  = (int*)take(4 * 80 * 4);             // [it][flag,thr,dropcnt,drops..]
  u16*      wtH     = (u16*)take((size_t)5 * 12 * 4096 * 2);  // pre-tiled bf16-hi weights
  u16*      wtM     = (u16*)take((size_t)5 * 12 * 4096 * 2);  // pre-tiled bf16-mid weights
  u16*      wtL     = (u16*)take((size_t)5 * 12 * 4096 * 2);  // pre-tiled bf16-lo weights
  int*      bar     = (int*)take(64);                     // [it][3] spin-barrier counters
  (void)ws_size; (void)n_in; (void)out_size;

  const int TB  = 256;
  const int gE  = (E + TB - 1) / TB;
  const int gN  = (N + TB - 1) / TB;
  const int gN4 = (N + 3) / 4;   // one wave per node
  const int gM  = (N + 127) / 128;

  (void)hipMemsetAsync(flag, 0, 4, stream);
  zero_detect_kernel<<<gN, TB, 0, stream>>>(degcur, hists, rep, candcnt4, bar, N, ei, flag, E);
  cvt_deg_kernel<<<gE, TB, 0, stream>>>(ei, flag, src32, dst32, degcur, E);
  scan_rowptr_kernel<<<1, 1024, 0, stream>>>(degcur, rowptr, N);
  scatter_kernel<<<gE, TB, 0, stream>>>(src32, degcur, eids, E);
  sort_eids_kernel<<<gN, TB, 0, stream>>>(rowptr, eids, N);
  wprep_kernel<<<56, 384, 0, stream>>>(W, a, wa_all, xw, wtH, wtM, wtL);
  et4_kernel<<<gE, TB, 0, stream>>>(ete, wa_all, et4, E);
  gemm_mfma_kernel<<<gM, 256, 0, stream>>>(x, nullptr, nullptr, nullptr, wtH, wtM, wtL, xb,
                                           xcA, N, 1, wa_all, pa, qa, nullptr, nullptr,
                                           nullptr, 1);

  float* bufs[2] = {xcA, xcB};
  for (int it = 0; it < 4; ++it) {
    const float* xc = bufs[it & 1];
    float* xn = bufs[(it & 1) ^ 1];
    unsigned* hists_it = hists + it * 1024;
    unsigned* rep_it = rep + it * 8192;
    int* hdr_it = header + it * 80;
    const u16* wH = wtH + (size_t)(it + 1) * 12 * 4096;
    const u16* wM = wtM + (size_t)(it + 1) * 12 * 4096;
    const u16* wL = wtL + (size_t)(it + 1) * 12 * 4096;

    softmax_kernel<<<gN4, TB, 0, stream>>>(rowptr, eids, dst32, pa, qa, et4, it, E, alpha,
                                           rep_it, N);
    select_kernel<<<384, 256, 0, stream>>>(alpha, rep_it, hists_it, Ktop, candList,
                                           candcnt4 + it, hdr_it, amask, E, bar + it * 3);
    agg_kernel<<<gN4, TB, 0, stream>>>(rowptr, eids, dst32, alpha, amask, hdr_it,
                                       xc, ete, sa, vbuf, tbuf, N);
    if (it < 3)
      gemm_mfma_kernel<<<gM, 256, 0, stream>>>(xc, vbuf, tbuf, sa, wH, wM, wL, nullptr, xn,
                                               N, 3, wa_all + (it + 1) * 384, pa, qa,
                                               nullptr, nullptr, nullptr, 1);
    else
      gemm_mfma_kernel<<<gM, 256, 0, stream>>>(xc, vbuf, tbuf, sa, wH, wM, wL, nullptr, xn,
                                               N, 3, nullptr, pa, qa, gamma, beta, out, 2);
  }
}

// Round 10
// 853.502 us; speedup vs baseline: 1.6396x; 1.6396x over previous
//
#include <hip/hip_runtime.h>
#include <math.h>

#define DOUT 128

typedef unsigned short u16;
typedef __attribute__((ext_vector_type(8))) short bf16x8;   // 8 bf16 bit-patterns (4 VGPRs)
typedef __attribute__((ext_vector_type(4))) float f32x4;

static __device__ __forceinline__ f32x4 mfma16x16x32(bf16x8 a, bf16x8 b, f32x4 c) {
  return __builtin_amdgcn_mfma_f32_16x16x32_bf16(a, b, c, 0, 0, 0);
}

static __device__ __forceinline__ short bf16i(int v) {   // exact for |v| <= 256
  return (short)(__float_as_uint((float)v) >> 16);
}

// ---------- wave (64-lane) reductions ----------
static __device__ __forceinline__ float wsum64(float v) {
#pragma unroll
  for (int off = 32; off > 0; off >>= 1) v += __shfl_xor(v, off, 64);
  return v;
}
static __device__ __forceinline__ float wmax64(float v) {
#pragma unroll
  for (int off = 32; off > 0; off >>= 1) v = fmaxf(v, __shfl_xor(v, off, 64));
  return v;
}
// sum across the 4 lanes sharing (lane&15)  (lane bits 4,5)
static __device__ __forceinline__ float rsumg(float v) {
  v += __shfl_xor(v, 16, 64);
  v += __shfl_xor(v, 32, 64);
  return v;
}

// 3-way RNE bf16 split: x == h + m + l + eps, |eps| <= 2^-25 |x|  (manual, cold path)
static __device__ __forceinline__ void split3(float x, u16& h, u16& m, u16& l) {
  unsigned u = __float_as_uint(x);
  unsigned rh = u + 0x7FFFu + ((u >> 16) & 1u);
  h = (u16)(rh >> 16);
  float hf = __uint_as_float(rh & 0xFFFF0000u);
  float d1 = x - hf;
  unsigned v = __float_as_uint(d1);
  unsigned rm = v + 0x7FFFu + ((v >> 16) & 1u);
  m = (u16)(rm >> 16);
  float mf = __uint_as_float(rm & 0xFFFF0000u);
  float d2 = d1 - mf;
  unsigned w2 = __float_as_uint(d2);
  unsigned rl = w2 + 0x7FFFu + ((w2 >> 16) & 1u);
  l = (u16)(rl >> 16);
}

// hot-path split via v_cvt_pk_bf16_f32 (HW RNE; packs lo=cvt(x0), hi=cvt(x1))
static __device__ __forceinline__ void split3pk(float x0, float x1,
                                                unsigned& h, unsigned& m, unsigned& l) {
  unsigned hp, mp, lp;
  asm("v_cvt_pk_bf16_f32 %0, %1, %2" : "=v"(hp) : "v"(x0), "v"(x1));
  float d0 = x0 - __uint_as_float(hp << 16);
  float d1 = x1 - __uint_as_float(hp & 0xFFFF0000u);
  asm("v_cvt_pk_bf16_f32 %0, %1, %2" : "=v"(mp) : "v"(d0), "v"(d1));
  float e0 = d0 - __uint_as_float(mp << 16);
  float e1 = d1 - __uint_as_float(mp & 0xFFFF0000u);
  asm("v_cvt_pk_bf16_f32 %0, %1, %2" : "=v"(lp) : "v"(e0), "v"(e1));
  h = hp; m = mp; l = lp;
}
static __device__ __forceinline__ void split34pk(float4 v, uint2& h, uint2& m, uint2& lo) {
  split3pk(v.x, v.y, h.x, m.x, lo.x);
  split3pk(v.z, v.w, h.y, m.y, lo.y);
}

// ---------- setup: zero deg/hists/replicas/candcnt + dtype detect (merged) ----------
__global__ void zero_detect_kernel(int* __restrict__ degcur, unsigned* __restrict__ hists,
                                   unsigned* __restrict__ rep, int* __restrict__ candcnt4,
                                   int N, const void* __restrict__ ei, int* __restrict__ flag,
                                   int E) {
  int i = blockIdx.x * blockDim.x + threadIdx.x;
  if (i < N) degcur[i] = 0;
  if (i < 4096) hists[i] = 0u;
  if (i < 32768) rep[i] = 0u;
  if (i < 4) candcnt4[i] = 0;
  const int* p = (const int*)ei;
  int lim = (E < 65536) ? E : 65536;
  int any = 0;
  for (int j = i; j < lim; j += gridDim.x * blockDim.x) any |= (p[2 * j + 1] != 0);
  if (__any(any))
    if ((threadIdx.x & 63) == 0 && any) atomicOr(flag, 1);
}

// ---------- cvt + degree count ----------
__global__ void cvt_deg_kernel(const void* __restrict__ ei, const int* __restrict__ flag,
                               int* __restrict__ src, int* __restrict__ dst,
                               int* __restrict__ degcur, int E) {
  int i = blockIdx.x * blockDim.x + threadIdx.x;
  if (i >= E) return;
  int s, d;
  if (*flag) { const int* p = (const int*)ei; s = p[i]; d = p[E + i]; }
  else { const long long* p = (const long long*)ei; s = (int)p[i]; d = (int)p[(size_t)E + i]; }
  src[i] = s;
  dst[i] = d;
  atomicAdd(&degcur[s], 1);
}

// ---------- rowptr scan (also leaves cursor copy in degcur) ----------
__global__ void scan_rowptr_kernel(int* __restrict__ degcur, int* __restrict__ rowptr, int N) {
  const int tid = threadIdx.x;  // 1024
  const int lane = tid & 63, wid = tid >> 6;
  __shared__ int wsumS[16];
  __shared__ int sbase;
  if (tid == 0) sbase = 0;
  __syncthreads();
  for (int base = 0; base < N; base += 1024) {
    int i = base + tid;
    int v = (i < N) ? degcur[i] : 0;
    int x = v;
#pragma unroll
    for (int off = 1; off < 64; off <<= 1) {
      int y = __shfl_up(x, off, 64);
      if (lane >= off) x += y;
    }
    if (lane == 63) wsumS[wid] = x;
    __syncthreads();
    int wbase = 0;
#pragma unroll
    for (int w2 = 0; w2 < 16; ++w2) wbase += (w2 < wid) ? wsumS[w2] : 0;
    int excl = sbase + wbase + x - v;
    if (i < N) { rowptr[i] = excl; degcur[i] = excl; }
    __syncthreads();
    if (tid == 1023) sbase += wbase + x;
    __syncthreads();
  }
  if (tid == 0) rowptr[N] = sbase;
}

__global__ void scatter_kernel(const int* __restrict__ src, int* __restrict__ cursor,
                               int* __restrict__ eids, int E) {
  int e = blockIdx.x * blockDim.x + threadIdx.x;
  if (e >= E) return;
  int p = atomicAdd(&cursor[src[e]], 1);
  eids[p] = e;
}

// ---------- determinism: sort each segment's edge ids ascending (thread/node) ----------
__global__ void sort_eids_kernel(const int* __restrict__ rowptr, int* __restrict__ eids, int N) {
  int n = blockIdx.x * blockDim.x + threadIdx.x;
  if (n >= N) return;
  int p0 = rowptr[n], p1 = rowptr[n + 1];
  for (int i = p0 + 1; i < p1; ++i) {
    int key = eids[i];
    int j = i - 1;
    while (j >= p0 && eids[j] > key) { eids[j + 1] = eids[j]; --j; }
    eids[j + 1] = key;
  }
}

// ---------- merged: wa_all (blocks 0..3) + weight pre-split/tile with mu perm (blocks 4..55) ----
// RUNTIME k-map calibration: 32 exact-integer MFMA probes measure mu(t) = hA^-1(hB(t)).
// Storing B slot t <- B[k=mu(t)] equalizes the effective k-permutations for ANY hA,hB.
__global__ void wprep_kernel(const float* __restrict__ W, const float* __restrict__ a,
                             float* __restrict__ wa_all, const float* __restrict__ xw,
                             u16* __restrict__ wtH, u16* __restrict__ wtM,
                             u16* __restrict__ wtL) {
  int blk = blockIdx.x;  // 0..55
  int tid = threadIdx.x; // 384
  if (blk < 4) {
    int it = blk, k = tid;
    const float* row = W + ((size_t)it * 384 + k) * DOUT;
    const float* ai = a + (size_t)it * DOUT;
    float acc = 0.f;
    for (int j = 0; j < DOUT; ++j) acc = fmaf(row[j], ai[j], acc);
    wa_all[it * 384 + k] = acc;
    return;
  }
  __shared__ int muS[32];
  {
    int lw = tid & 63, g = lw >> 4;
    bf16x8 aEnc;
#pragma unroll
    for (int j = 0; j < 8; ++j) aEnc[j] = bf16i(8 * g + j + 1);   // A-slot index encode
    f32x4 z = {0.f, 0.f, 0.f, 0.f};
    for (int t0 = 0; t0 < 32; ++t0) {
      int g0 = t0 >> 3, j0 = t0 & 7;
      bf16x8 bOne;
#pragma unroll
      for (int j = 0; j < 8; ++j)
        bOne[j] = (g == g0 && j == j0) ? (short)0x3F80 : (short)0;  // one-hot B slot t0
      f32x4 d = mfma16x16x32(aEnc, bOne, z);
      if (tid == t0) muS[t0] = ((int)(d[0] + 0.5f) - 1) & 31;
    }
  }
  __syncthreads();
  int b = blk - 4;  // 0..51
  int set, ks;
  const float* srcp;
  if (b < 4) { set = 0; ks = b; srcp = xw; }
  else { set = 1 + (b - 4) / 12; ks = (b - 4) % 12; srcp = W + (size_t)(set - 1) * 384 * DOUT; }
  size_t base = ((size_t)set * 12 + ks) * 4096;
  for (int i = tid; i < 4096; i += blockDim.x) {
    int col = i >> 5, t = i & 31;
    float x = srcp[(size_t)(ks * 32 + muS[t]) * DOUT + col];   // k pre-permuted by mu
    u16 h, m, l;
    split3(x, h, m, l);
    wtH[base + i] = h;
    wtM[base + i] = m;
    wtL[base + i] = l;
  }
}

// ---------- et4[it][e] = ete[e]·wa3(it), planar output ----------
__global__ __launch_bounds__(256) void et4_kernel(const float* __restrict__ ete,
                                                  const float* __restrict__ wa_all,
                                                  float* __restrict__ et4, int E) {
  __shared__ float4 w3s[4][32];
  int tid = threadIdx.x;
  if (tid < 128) {
    int it = tid >> 5, k4 = tid & 31;
    const float* base = wa_all + it * 384 + 256 + k4 * 4;
    w3s[it][k4] = make_float4(base[0], base[1], base[2], base[3]);
  }
  __syncthreads();
  int e = blockIdx.x * blockDim.x + tid;
  if (e >= E) return;
  const float4* row = (const float4*)(ete + (size_t)e * DOUT);
  float a0 = 0.f, a1 = 0.f, a2 = 0.f, a3 = 0.f;
#pragma unroll
  for (int k4 = 0; k4 < 32; ++k4) {
    float4 r = row[k4];
    float4 w0 = w3s[0][k4], w1 = w3s[1][k4], w2 = w3s[2][k4], w3v = w3s[3][k4];
    a0 = fmaf(r.x, w0.x, fmaf(r.y, w0.y, fmaf(r.z, w0.z, fmaf(r.w, w0.w, a0))));
    a1 = fmaf(r.x, w1.x, fmaf(r.y, w1.y, fmaf(r.z, w1.z, fmaf(r.w, w1.w, a1))));
    a2 = fmaf(r.x, w2.x, fmaf(r.y, w2.y, fmaf(r.z, w2.z, fmaf(r.w, w2.w, a2))));
    a3 = fmaf(r.x, w3v.x, fmaf(r.y, w3v.y, fmaf(r.z, w3v.z, fmaf(r.w, w3v.w, a3))));
  }
  et4[e] = a0;
  et4[(size_t)E + e] = a1;
  et4[(size_t)2 * E + e] = a2;
  et4[(size_t)3 * E + e] = a3;
}

// ---------- fused score + segment softmax + REPLICATED hist level 0 ----------
__global__ __launch_bounds__(256) void softmax_kernel(
    const int* __restrict__ rowptr, const int* __restrict__ eids, const int* __restrict__ dst,
    const float* __restrict__ pa, const float* __restrict__ qa, const float* __restrict__ et4,
    int it, int E, float* __restrict__ alpha, unsigned* __restrict__ rep0, int N) {
  __shared__ unsigned lh[256];
  int tid = threadIdx.x;
  lh[tid] = 0u;
  __syncthreads();
  const float* etp = et4 + (size_t)it * E;
  int w = (int)(((size_t)blockIdx.x * blockDim.x + tid) >> 6);
  int lane = tid & 63;
  if (w < N) {
    int p0 = rowptr[w], p1 = rowptr[w + 1];
    int deg = p1 - p0;
    if (deg > 0) {
      float pan = pa[w];
      if (deg <= 64) {
        int p = p0 + lane;
        int e = -1;
        float sv = -3.402823466e38f;
        if (p < p1) {
          e = eids[p];
          float s = pan + qa[dst[e]] + etp[e];
          sv = (s >= 0.f) ? s : 0.2f * s;
        }
        float m = wmax64(sv);
        float ee = (e >= 0) ? expf(sv - m) : 0.f;
        float den = 0.f;
        for (int i = 0; i < deg; ++i) den += __shfl(ee, i, 64);  // ordered sum
        den += 1e-16f;
        if (e >= 0) {
          float av = ee / den;
          alpha[e] = av;
          atomicAdd(&lh[__float_as_uint(av) >> 24], 1u);
        }
      } else if (deg <= 256) {
        float sv[4]; int ev[4];
#pragma unroll
        for (int u = 0; u < 4; ++u) {
          int p = p0 + u * 64 + lane;
          if (p < p1) {
            int e = eids[p];
            ev[u] = e;
            float s = pan + qa[dst[e]] + etp[e];
            sv[u] = (s >= 0.f) ? s : 0.2f * s;
          } else { ev[u] = -1; sv[u] = -3.402823466e38f; }
        }
        float m = fmaxf(fmaxf(sv[0], sv[1]), fmaxf(sv[2], sv[3]));
        m = wmax64(m);
        float ssum = 0.f;
#pragma unroll
        for (int u = 0; u < 4; ++u)
          if (ev[u] >= 0) { sv[u] = expf(sv[u] - m); ssum += sv[u]; }
        ssum = wsum64(ssum);
        float den = ssum + 1e-16f;
#pragma unroll
        for (int u = 0; u < 4; ++u)
          if (ev[u] >= 0) {
            float av = sv[u] / den;
            alpha[ev[u]] = av;
            atomicAdd(&lh[__float_as_uint(av) >> 24], 1u);
          }
      } else {
        float m = -3.402823466e38f;
        for (int p = p0 + lane; p < p1; p += 64) {
          int e = eids[p];
          float s = pan + qa[dst[e]] + etp[e];
          s = (s >= 0.f) ? s : 0.2f * s;
          m = fmaxf(m, s);
        }
        m = wmax64(m);
        float ssum = 0.f;
        for (int p = p0 + lane; p < p1; p += 64) {
          int e = eids[p];
          float s = pan + qa[dst[e]] + etp[e];
          s = (s >= 0.f) ? s : 0.2f * s;
          ssum += expf(s - m);
        }
        ssum = wsum64(ssum);
        float den = ssum + 1e-16f;
        for (int p = p0 + lane; p < p1; p += 64) {
          int e = eids[p];
          float s = pan + qa[dst[e]] + etp[e];
          s = (s >= 0.f) ? s : 0.2f * s;
          float av = expf(s - m) / den;
          alpha[e] = av;
          atomicAdd(&lh[__float_as_uint(av) >> 24], 1u);
        }
      }
    }
  }
  __syncthreads();
  if (lh[tid]) atomicAdd(&rep0[(blockIdx.x & 31) * 256 + tid], lh[tid]);
}

// ---------- single-level 256-bin scan (reads hist via plain loads) ----------
__device__ __forceinline__ void scan256_one(const unsigned* __restrict__ hist, unsigned krem_in,
                                            unsigned* lds, unsigned* res,
                                            unsigned& bin, unsigned& krem_out) {
  int t = threadIdx.x;
  lds[t] = hist[t];
  __syncthreads();
  for (int off = 1; off < 256; off <<= 1) {
    unsigned add = (t + off < 256) ? lds[t + off] : 0u;
    __syncthreads();
    lds[t] += add;
    __syncthreads();
  }
  {
    unsigned above = (t == 255) ? 0u : lds[t + 1];
    if (lds[t] >= krem_in && above < krem_in) { res[0] = (unsigned)t; res[1] = krem_in - above; }
  }
  __syncthreads();
  bin = res[0];
  krem_out = res[1];
  __syncthreads();
}

// ---------- hist1: reduce 32 replicas -> level-0 scan; write scanres0; build level-1 ----------
// scanres layout per it: [0]=pref8 (bin0), [1]=krem0, [2]=pref16, [3]=krem1,
//                        [4]=pref24, [5]=krem2   (kernel-boundary ordering = coherence)
__global__ __launch_bounds__(256) void hist1_kernel(const float* __restrict__ alpha,
                                                    const unsigned* __restrict__ rep0,
                                                    unsigned* __restrict__ hists_it,
                                                    unsigned* __restrict__ scanres,
                                                    unsigned Ktop, int E) {
  __shared__ unsigned lds[256], res2[2], lh[256];
  int t = threadIdx.x;
  unsigned v = 0u;
#pragma unroll
  for (int r = 0; r < 32; ++r) v += rep0[r * 256 + t];
  lds[t] = v;
  __syncthreads();
  for (int off = 1; off < 256; off <<= 1) {
    unsigned add = (t + off < 256) ? lds[t + off] : 0u;
    __syncthreads();
    lds[t] += add;
    __syncthreads();
  }
  {
    unsigned above = (t == 255) ? 0u : lds[t + 1];
    if (lds[t] >= Ktop && above < Ktop) { res2[0] = (unsigned)t; res2[1] = Ktop - above; }
  }
  __syncthreads();
  unsigned bin0 = res2[0];
  if (blockIdx.x == 0 && t == 0) { scanres[0] = bin0; scanres[1] = res2[1]; }
  lh[t] = 0u;
  __syncthreads();
  unsigned* myh = hists_it + 256;
  for (int e = blockIdx.x * blockDim.x + t; e < E; e += gridDim.x * blockDim.x) {
    unsigned b = __float_as_uint(alpha[e]);
    if ((b >> 24) == bin0) atomicAdd(&lh[(b >> 16) & 0xFFu], 1u);
  }
  __syncthreads();
  if (lh[t]) atomicAdd(&myh[t], lh[t]);
}

// ---------- hist2: scan level-1 (using scanres0); write scanres1; build level-2 ----------
__global__ __launch_bounds__(256) void hist2_kernel(const float* __restrict__ alpha,
                                                    unsigned* __restrict__ hists_it,
                                                    unsigned* __restrict__ scanres, int E) {
  __shared__ unsigned lds[256], res2[2], lh[256];
  int t = threadIdx.x;
  unsigned pref8 = scanres[0], krem0 = scanres[1];
  unsigned bin1, krem1;
  scan256_one(hists_it + 256, krem0, lds, res2, bin1, krem1);
  unsigned pref16 = (pref8 << 8) | bin1;
  if (blockIdx.x == 0 && t == 0) { scanres[2] = pref16; scanres[3] = krem1; }
  lh[t] = 0u;
  __syncthreads();
  unsigned* myh = hists_it + 512;
  for (int e = blockIdx.x * blockDim.x + t; e < E; e += gridDim.x * blockDim.x) {
    unsigned b = __float_as_uint(alpha[e]);
    if ((b >> 16) == pref16) atomicAdd(&lh[(b >> 8) & 0xFFu], 1u);
  }
  __syncthreads();
  if (lh[t]) atomicAdd(&myh[t], lh[t]);
}

// ---------- hist3 + collect: scan level-2; write scanres2; build level-3 + candidates ----------
__global__ __launch_bounds__(256) void hist3c_kernel(const float* __restrict__ alpha,
                                                     unsigned* __restrict__ hists_it,
                                                     unsigned* __restrict__ scanres,
                                                     int* __restrict__ candList,
                                                     int* __restrict__ candCnt, int E) {
  __shared__ unsigned lds[256], res2[2], lh[256];
  int t = threadIdx.x;
  unsigned pref16 = scanres[2], krem1 = scanres[3];
  unsigned bin2, krem2;
  scan256_one(hists_it + 512, krem1, lds, res2, bin2, krem2);
  unsigned pref24 = (pref16 << 8) | bin2;
  if (blockIdx.x == 0 && t == 0) { scanres[4] = pref24; scanres[5] = krem2; }
  lh[t] = 0u;
  __syncthreads();
  unsigned* myh = hists_it + 768;
  for (int e = blockIdx.x * blockDim.x + t; e < E; e += gridDim.x * blockDim.x) {
    unsigned b = __float_as_uint(alpha[e]);
    if ((b >> 8) == pref24) {
      atomicAdd(&lh[b & 0xFFu], 1u);
      int p = atomicAdd(candCnt, 1);
      if (p < 4096) candList[p] = e;
    }
  }
  __syncthreads();
  if (lh[t]) atomicAdd(&myh[t], lh[t]);
}

// ---------- resolve24 (1 block): scan level-3; thr + tiny drop-list; adversarial fallback ----
__global__ __launch_bounds__(1024) void resolve24_kernel(
    const float* __restrict__ alpha, float* __restrict__ amask,
    const unsigned* __restrict__ hists_it, const unsigned* __restrict__ scanres,
    const int* __restrict__ candList, const int* __restrict__ candCnt,
    int* __restrict__ header, int E) {
  __shared__ unsigned lds[256], res2[2];
  int tid = threadIdx.x;
  unsigned pref24 = scanres[4], krem2 = scanres[5];
  // scan level-3 with first 256 threads' data; all 1024 threads participate in barriers
  {
    int t = tid;
    if (t < 256) lds[t] = hists_it[768 + t];
    __syncthreads();
    for (int off = 1; off < 256; off <<= 1) {
      unsigned add = 0u;
      if (t < 256 && t + off < 256) add = lds[t + off];
      __syncthreads();
      if (t < 256) lds[t] += add;
      __syncthreads();
    }
    if (t < 256) {
      unsigned above = (t == 255) ? 0u : lds[t + 1];
      if (lds[t] >= krem2 && above < krem2) { res2[0] = (unsigned)t; res2[1] = krem2 - above; }
    }
    __syncthreads();
  }
  unsigned thr = (pref24 << 8) | res2[0];
  int needT = (int)res2[1];
  __syncthreads();
  int cc = *candCnt;
  __shared__ int tiel[4096];
  __shared__ int tiec;
  if (tid == 0) tiec = 0;
  __syncthreads();
  if (cc <= 4096) {
    for (int i = tid; i < cc; i += blockDim.x) {
      int e = candList[i];
      if (__float_as_uint(alpha[e]) == thr) { int p = atomicAdd(&tiec, 1); tiel[p] = e; }
    }
    __syncthreads();
    int ce = tiec;
    int dropc = ce - needT;
    if (dropc <= 0) {
      if (tid == 0) { header[0] = 0; header[1] = (int)thr; header[2] = 0; }
      return;
    }
    if (dropc <= 64) {
      int sortN = 64;
      while (sortN < ce) sortN <<= 1;
      for (int i = tid; i < sortN; i += blockDim.x)
        if (i >= ce) tiel[i] = 0x7fffffff;
      __syncthreads();
      for (int k = 2; k <= sortN; k <<= 1) {
        for (int j = k >> 1; j > 0; j >>= 1) {
          for (int i = tid; i < sortN; i += blockDim.x) {
            int ixj = i ^ j;
            if (ixj > i) {
              int v0 = tiel[i], v1 = tiel[ixj];
              bool up = ((i & k) == 0);
              if ((v0 > v1) == up) { tiel[i] = v1; tiel[ixj] = v0; }
            }
          }
          __syncthreads();
        }
      }
      if (tid == 0) { header[0] = 0; header[1] = (int)thr; header[2] = dropc; }
      for (int i = tid; i < dropc; i += blockDim.x) header[3 + i] = tiel[needT + i];
      return;
    }
  }
  // adversarial fallback: write FULL amask deterministically (slow but correct)
  if (tid == 0) { header[0] = 1; }
  __shared__ int wtot[16];
  __shared__ int sbase;
  if (tid == 0) sbase = 0;
  __syncthreads();
  int lane = tid & 63, wid = tid >> 6;
  for (int base = 0; base < E; base += 1024) {
    int e = base + tid;
    float a = 0.f; int f = 0; unsigned b = 0u;
    if (e < E) { a = alpha[e]; b = __float_as_uint(a); f = (b == thr) ? 1 : 0; }
    int x = f;
#pragma unroll
    for (int off = 1; off < 64; off <<= 1) {
      int y = __shfl_up(x, off, 64);
      if (lane >= off) x += y;
    }
    if (lane == 63) wtot[wid] = x;
    __syncthreads();
    int wbase = 0;
#pragma unroll
    for (int w2 = 0; w2 < 16; ++w2) wbase += (w2 < wid) ? wtot[w2] : 0;
    if (e < E) {
      float outv = 0.f;
      if (b > thr) outv = a;
      else if (f && (sbase + wbase + x - f) < needT) outv = a;
      amask[e] = outv;
    }
    __syncthreads();
    if (tid == 1023) sbase += wbase + x;
    __syncthreads();
  }
}

// ---------- per-edge weight: threshold alpha inline (flag=1 -> amask fallback) ----------
static __device__ __forceinline__ float edge_w(const float* __restrict__ alpha,
                                               const float* __restrict__ amask,
                                               const int* __restrict__ hdr, int flg,
                                               unsigned thr, int dc, int e) {
  if (flg) return amask[e];
  float av = alpha[e];
  unsigned b = __float_as_uint(av);
  if (b > thr) return av;
  if (b == thr) {
    for (int j = 0; j < dc; ++j)
      if (hdr[3 + j] == e) return 0.f;
    return av;
  }
  return 0.f;
}

// ---------- aggregation (wave per node, split halves, metadata prefetch) ----------
__global__ void agg_kernel(const int* __restrict__ rowptr, const int* __restrict__ eids,
                           const int* __restrict__ dst, const float* __restrict__ alpha,
                           const float* __restrict__ amask, const int* __restrict__ hdr,
                           const float* __restrict__ xc, const float* __restrict__ ete,
                           float* __restrict__ sa, float* __restrict__ vbuf,
                           float* __restrict__ tbuf, int N) {
  int w = (int)(((size_t)blockIdx.x * blockDim.x + threadIdx.x) >> 6);
  int lane = threadIdx.x & 63;
  if (w >= N) return;
  const int flg = hdr[0];
  const unsigned thr = (unsigned)hdr[1];
  const int dc = hdr[2];
  int p0 = rowptr[w], p1 = rowptr[w + 1];
  int deg = p1 - p0;
  const int half = lane >> 5;
  const int l32 = lane & 31;
  const float4* xc4 = (const float4*)xc;
  const float4* et4p = (const float4*)ete;
  float4 acc = make_float4(0.f, 0.f, 0.f, 0.f);
  float s = 0.f;
  if (deg <= 64) {
    int p = p0 + lane;
    int e = -1; float am = 0.f; int dd = 0;
    if (p < p1) { e = eids[p]; am = edge_w(alpha, amask, hdr, flg, thr, dc, e); dd = dst[e]; }
    for (int i = 0; i < deg; ++i) {
      float a = __shfl(am, i, 64);
      if (a != 0.f) {
        int ei = __shfl(e, i, 64);
        int di = __shfl(dd, i, 64);
        const float4* b = half ? (et4p + (size_t)ei * 32) : (xc4 + (size_t)di * 32);
        float4 r = b[l32];
        acc.x = fmaf(a, r.x, acc.x); acc.y = fmaf(a, r.y, acc.y);
        acc.z = fmaf(a, r.z, acc.z); acc.w = fmaf(a, r.w, acc.w);
        s += a;
      }
    }
  } else {
    for (int p = p0; p < p1; ++p) {
      int e0 = eids[p];
      float a0 = edge_w(alpha, amask, hdr, flg, thr, dc, e0);
      if (a0 != 0.f) {
        int d0 = dst[e0];
        const float4* b0 = half ? (et4p + (size_t)e0 * 32) : (xc4 + (size_t)d0 * 32);
        float4 r = b0[l32];
        acc.x = fmaf(a0, r.x, acc.x); acc.y = fmaf(a0, r.y, acc.y);
        acc.z = fmaf(a0, r.z, acc.z); acc.w = fmaf(a0, r.w, acc.w);
        s += a0;
      }
    }
  }
  if (half == 0) ((float4*)vbuf)[(size_t)w * 32 + l32] = acc;
  else           ((float4*)tbuf)[(size_t)w * 32 + l32] = acc;
  if (lane == 0) sa[w] = s;
}

// ---------- MFMA GEMM: C[Nx128] = concat(sca*A0|A1|A2)[N x 128*nseg] @ B (+bias)
// fp32 emulated via 3-way RNE bf16 split (6 product terms, residual ~2^-24 rel).
// SELF-CALIBRATING on all lane maps (k-maps via mu-permuted B; C/D via in-kernel probes
// + measured-map LDS slab epilogue).  cvt_pk hot split + 1-step register prefetch.
//            epi=1: fused pa/qa for next iter;  epi=2: fused ELU+LayerNorm -> outp ----------
__global__ __launch_bounds__(256) void gemm_mfma_kernel(
    const float* __restrict__ A0, const float* __restrict__ A1, const float* __restrict__ A2,
    const float* __restrict__ sca, const u16* __restrict__ wtH, const u16* __restrict__ wtM,
    const u16* __restrict__ wtL, const float* __restrict__ bias, float* __restrict__ C,
    int N, int nseg,
    const float* __restrict__ wa_next, float* __restrict__ pa, float* __restrict__ qa,
    const float* __restrict__ gamma, const float* __restrict__ beta,
    float* __restrict__ outp, int epi) {
  __shared__ __align__(16) char smem[61440];
  u16 (*AsH)[40] = (u16(*)[40])(smem);
  u16 (*AsM)[40] = (u16(*)[40])(smem + 10240);
  u16 (*AsL)[40] = (u16(*)[40])(smem + 20480);
  u16 (*BsH)[40] = (u16(*)[40])(smem + 30720);
  u16 (*BsM)[40] = (u16(*)[40])(smem + 40960);
  u16 (*BsL)[40] = (u16(*)[40])(smem + 51200);
  const int tid = threadIdx.x;
  const int m0 = blockIdx.x * 128;
  const int K = DOUT * nseg;
  const int w = tid >> 6, l = tid & 63;
  const int cb = l & 15, g = l >> 4;

  // --- C/D lane-map calibration (2 exact-integer MFMAs) ---
  int rowlab[4], collab[4];
  {
    bf16x8 enc, ones;
#pragma unroll
    for (int j = 0; j < 8; ++j) { enc[j] = bf16i(cb + 1); ones[j] = (short)0x3F80; }
    f32x4 z = {0.f, 0.f, 0.f, 0.f};
    f32x4 dR = mfma16x16x32(enc, ones, z);   // D = 32*(row+1)
    f32x4 dC = mfma16x16x32(ones, enc, z);   // D = 32*(col+1)
#pragma unroll
    for (int r = 0; r < 4; ++r) {
      rowlab[r] = ((int)(dR[r] * (1.f / 32.f) + 0.5f) - 1) & 15;
      collab[r] = ((int)(dC[r] * (1.f / 32.f) + 0.5f) - 1) & 15;
    }
  }

  f32x4 acc[2][8];
#pragma unroll
  for (int i = 0; i < 2; ++i)
#pragma unroll
    for (int j = 0; j < 8; ++j) acc[i][j] = (f32x4){0.f, 0.f, 0.f, 0.f};

  // staging role: thread handles A row (tid>>1), 16 floats at col half*16
  const int srow = tid >> 1, shalf = tid & 1;
  const int grow_s = m0 + srow;
  float scv = 1.f;
  if (sca && grow_s < N) scv = sca[grow_s];

  auto loadA = [&](int kc, float4& v0, float4& v1, float4& v2, float4& v3) {
    const int seg = kc >> 7;
    const float* Ap = (seg == 0) ? A0 : (seg == 1) ? A1 : A2;
    v0 = make_float4(0.f, 0.f, 0.f, 0.f); v1 = v0; v2 = v0; v3 = v0;
    if (grow_s < N) {
      const float4* p = (const float4*)(Ap + (size_t)grow_s * DOUT + (kc & 127) + shalf * 16);
      v0 = p[0]; v1 = p[1]; v2 = p[2]; v3 = p[3];
      if (seg == 0 && sca) {
        v0.x *= scv; v0.y *= scv; v0.z *= scv; v0.w *= scv;
        v1.x *= scv; v1.y *= scv; v1.z *= scv; v1.w *= scv;
        v2.x *= scv; v2.y *= scv; v2.z *= scv; v2.w *= scv;
        v3.x *= scv; v3.y *= scv; v3.z *= scv; v3.w *= scv;
      }
    }
  };
  auto loadB = [&](int kc, uint4& h0, uint4& h1, uint4& m0u, uint4& m1u, uint4& l0u,
                   uint4& l1u) {
    size_t sb = (size_t)(kc >> 5) << 12;
    const uint4* gh = (const uint4*)(wtH + sb) + tid * 2;
    const uint4* gm = (const uint4*)(wtM + sb) + tid * 2;
    const uint4* gl = (const uint4*)(wtL + sb) + tid * 2;
    h0 = gh[0]; h1 = gh[1];
    m0u = gm[0]; m1u = gm[1];
    l0u = gl[0]; l1u = gl[1];
  };

  float4 av0, av1, av2, av3, nv0, nv1, nv2, nv3;
  uint4 bh0, bh1, bm0u, bm1u, bl0u, bl1u, nh0, nh1, nm0, nm1, nl0, nl1;
  loadA(0, av0, av1, av2, av3);
  loadB(0, bh0, bh1, bm0u, bm1u, bl0u, bl1u);

  const int nks = K >> 5;
  for (int ks = 0; ks < nks; ++ks) {
    const int kc = ks << 5;
    {
      uint2 h0, m0v, l0, h1, m1v, l1, h2, m2v, l2, h3, m3v, l3;
      split34pk(av0, h0, m0v, l0); split34pk(av1, h1, m1v, l1);
      split34pk(av2, h2, m2v, l2); split34pk(av3, h3, m3v, l3);
      *(uint4*)&AsH[srow][shalf * 16]     = make_uint4(h0.x, h0.y, h1.x, h1.y);
      *(uint4*)&AsH[srow][shalf * 16 + 8] = make_uint4(h2.x, h2.y, h3.x, h3.y);
      *(uint4*)&AsM[srow][shalf * 16]     = make_uint4(m0v.x, m0v.y, m1v.x, m1v.y);
      *(uint4*)&AsM[srow][shalf * 16 + 8] = make_uint4(m2v.x, m2v.y, m3v.x, m3v.y);
      *(uint4*)&AsL[srow][shalf * 16]     = make_uint4(l0.x, l0.y, l1.x, l1.y);
      *(uint4*)&AsL[srow][shalf * 16 + 8] = make_uint4(l2.x, l2.y, l3.x, l3.y);
      *(uint4*)&BsH[srow][shalf * 16]     = bh0;
      *(uint4*)&BsH[srow][shalf * 16 + 8] = bh1;
      *(uint4*)&BsM[srow][shalf * 16]     = bm0u;
      *(uint4*)&BsM[srow][shalf * 16 + 8] = bm1u;
      *(uint4*)&BsL[srow][shalf * 16]     = bl0u;
      *(uint4*)&BsL[srow][shalf * 16 + 8] = bl1u;
    }
    if (ks + 1 < nks) {
      loadA(kc + 32, nv0, nv1, nv2, nv3);
      loadB(kc + 32, nh0, nh1, nm0, nm1, nl0, nl1);
    }
    __syncthreads();
    bf16x8 aH0 = *(const bf16x8*)&AsH[w * 32 + cb][g * 8];
    bf16x8 aH1 = *(const bf16x8*)&AsH[w * 32 + 16 + cb][g * 8];
    bf16x8 aM0 = *(const bf16x8*)&AsM[w * 32 + cb][g * 8];
    bf16x8 aM1 = *(const bf16x8*)&AsM[w * 32 + 16 + cb][g * 8];
    bf16x8 aL0 = *(const bf16x8*)&AsL[w * 32 + cb][g * 8];
    bf16x8 aL1 = *(const bf16x8*)&AsL[w * 32 + 16 + cb][g * 8];
#pragma unroll
    for (int ct = 0; ct < 8; ++ct) {
      bf16x8 bH = *(const bf16x8*)&BsH[ct * 16 + cb][g * 8];
      bf16x8 bM = *(const bf16x8*)&BsM[ct * 16 + cb][g * 8];
      bf16x8 bL = *(const bf16x8*)&BsL[ct * 16 + cb][g * 8];
      acc[0][ct] = mfma16x16x32(aH0, bH, acc[0][ct]);
      acc[1][ct] = mfma16x16x32(aH1, bH, acc[1][ct]);
      acc[0][ct] = mfma16x16x32(aM0, bH, acc[0][ct]);
      acc[1][ct] = mfma16x16x32(aM1, bH, acc[1][ct]);
      acc[0][ct] = mfma16x16x32(aL0, bH, acc[0][ct]);
      acc[1][ct] = mfma16x16x32(aL1, bH, acc[1][ct]);
      acc[0][ct] = mfma16x16x32(aH0, bM, acc[0][ct]);
      acc[1][ct] = mfma16x16x32(aH1, bM, acc[1][ct]);
      acc[0][ct] = mfma16x16x32(aM0, bM, acc[0][ct]);
      acc[1][ct] = mfma16x16x32(aM1, bM, acc[1][ct]);
      acc[0][ct] = mfma16x16x32(aH0, bL, acc[0][ct]);
      acc[1][ct] = mfma16x16x32(aH1, bL, acc[1][ct]);
    }
    __syncthreads();
    av0 = nv0; av1 = nv1; av2 = nv2; av3 = nv3;
    bh0 = nh0; bh1 = nh1; bm0u = nm0; bm1u = nm1; bl0u = nl0; bl1u = nl1;
  }

  // ---- epilogue: measured-map scatter into per-wave LDS slab, canonical read-back ----
  float* slab = (float*)(smem + (size_t)w * 8448);  // [16][132] f32
  const int row16 = l & 15;
  const int csel = (l >> 4) * 32;
#pragma unroll
  for (int rt = 0; rt < 2; ++rt) {
#pragma unroll
    for (int ct = 0; ct < 8; ++ct)
#pragma unroll
      for (int r = 0; r < 4; ++r)
        slab[rowlab[r] * 132 + ct * 16 + collab[r]] = acc[rt][ct][r];
    __syncthreads();
    int grow = m0 + w * 32 + rt * 16 + row16;
    float v[32];
#pragma unroll
    for (int q = 0; q < 8; ++q) {
      float4 t4 = *(float4*)&slab[row16 * 132 + csel + q * 4];
      v[q * 4 + 0] = t4.x; v[q * 4 + 1] = t4.y; v[q * 4 + 2] = t4.z; v[q * 4 + 3] = t4.w;
    }
    if (bias) {
#pragma unroll
      for (int q = 0; q < 8; ++q) {
        float4 bb = *(const float4*)(bias + csel + q * 4);
        v[q * 4 + 0] += bb.x; v[q * 4 + 1] += bb.y; v[q * 4 + 2] += bb.z; v[q * 4 + 3] += bb.w;
      }
    }
    if (epi == 2) {  // ELU + LayerNorm -> outp
#pragma unroll
      for (int i = 0; i < 32; ++i) v[i] = (v[i] > 0.f) ? v[i] : expm1f(v[i]);
      float s = 0.f;
#pragma unroll
      for (int i = 0; i < 32; ++i) s += v[i];
      s = rsumg(s);
      float mu = s * (1.f / 128.f);
      float sq = 0.f;
#pragma unroll
      for (int i = 0; i < 32; ++i) { float d = v[i] - mu; sq += d * d; }
      sq = rsumg(sq);
      float rstd = rsqrtf(sq * (1.f / 128.f) + 1e-5f);
      if (grow < N) {
#pragma unroll
        for (int q = 0; q < 8; ++q) {
          float4 ga = *(const float4*)(gamma + csel + q * 4);
          float4 be = *(const float4*)(beta + csel + q * 4);
          float4 o;
          o.x = (v[q * 4 + 0] - mu) * rstd * ga.x + be.x;
          o.y = (v[q * 4 + 1] - mu) * rstd * ga.y + be.y;
          o.z = (v[q * 4 + 2] - mu) * rstd * ga.z + be.z;
          o.w = (v[q * 4 + 3] - mu) * rstd * ga.w + be.w;
          *(float4*)(outp + (size_t)grow * DOUT + csel + q * 4) = o;
        }
      }
    } else {
      if (grow < N) {
#pragma unroll
        for (int q = 0; q < 8; ++q)
          *(float4*)(C + (size_t)grow * DOUT + csel + q * 4) =
              make_float4(v[q * 4 + 0], v[q * 4 + 1], v[q * 4 + 2], v[q * 4 + 3]);
      }
      if (epi == 1) {  // pa/qa for next iteration's scores
        float pp = 0.f, qq = 0.f;
#pragma unroll
        for (int i = 0; i < 32; ++i) {
          pp = fmaf(v[i], wa_next[csel + i], pp);
          qq = fmaf(v[i], wa_next[128 + csel + i], qq);
        }
        pp = rsumg(pp);
        qq = rsumg(qq);
        if ((l >> 4) == 0 && grow < N) { pa[grow] = pp; qa[grow] = qq; }
      }
    }
    __syncthreads();
  }
}

extern "C" void kernel_launch(void* const* d_in, const int* in_sizes, int n_in,
                              void* d_out, int out_size, void* d_ws, size_t ws_size,
                              hipStream_t stream) {
  const int E = in_sizes[0] / 2;
  const int N = in_sizes[1] / DOUT;
  const unsigned Ktop = (unsigned)(E / 2);  // int(E * 0.5)

  const void*  ei    = d_in[0];
  const float* x     = (const float*)d_in[1];
  const float* ete   = (const float*)d_in[2];
  const float* W     = (const float*)d_in[3];
  const float* a     = (const float*)d_in[4];
  const float* xw    = (const float*)d_in[5];
  const float* xb    = (const float*)d_in[6];
  const float* gamma = (const float*)d_in[7];
  const float* beta  = (const float*)d_in[8];
  float* out = (float*)d_out;

  size_t off = 0;
  auto take = [&](size_t bytes) -> char* {
    char* p = (char*)d_ws + off;
    off += (bytes + 255) & ~(size_t)255;
    return p;
  };
  int*      src32   = (int*)take((size_t)E * 4);
  int*      dst32   = (int*)take((size_t)E * 4);
  int*      rowptr  = (int*)take(((size_t)N + 1) * 4);
  int*      degcur  = (int*)take((size_t)N * 4);
  int*      eids    = (int*)take((size_t)E * 4);
  float*    pa      = (float*)take((size_t)N * 4);
  float*    qa      = (float*)take((size_t)N * 4);
  float*    wa_all  = (float*)take(4 * 384 * 4);
  float*    alpha   = (float*)take((size_t)E * 4);
  float*    amask   = (float*)take((size_t)E * 4);
  float*    sa      = (float*)take((size_t)N * 4);
  float*    vbuf    = (float*)take((size_t)N * DOUT * 4);
  float*    tbuf    = (float*)take((size_t)N * DOUT * 4);
  float*    xcA     = (float*)take((size_t)N * DOUT * 4);
  float*    xcB     = (float*)take((size_t)N * DOUT * 4);
  float*    et4     = (float*)take((size_t)E * 4 * 4);
  unsigned* hists   = (unsigned*)take(4 * 4 * 256 * 4);   // [it][level][256]
  unsigned* rep     = (unsigned*)take(4 * 32 * 256 * 4);  // [it][replica][256]
  int*      candcnt4= (int*)take(64);
  int*      flag    = (int*)take(64);
  int*      candList= (int*)take(4096 * 4);
  int*      header  = (int*)take(4 * 80 * 4);             // [it][flag,thr,dropcnt,drops..]
  u16*      wtH     = (u16*)take((size_t)5 * 12 * 4096 * 2);  // pre-tiled bf16-hi weights
  u16*      wtM     = (u16*)take((size_t)5 * 12 * 4096 * 2);  // pre-tiled bf16-mid weights
  u16*      wtL     = (u16*)take((size_t)5 * 12 * 4096 * 2);  // pre-tiled bf16-lo weights
  unsigned* scanres = (unsigned*)take(4 * 8 * 4);         // [it][pref/krem per level]
  (void)ws_size; (void)n_in; (void)out_size;

  const int TB  = 256;
  const int gE  = (E + TB - 1) / TB;
  const int gN  = (N + TB - 1) / TB;
  const int gN4 = (N + 3) / 4;   // one wave per node
  const int gM  = (N + 127) / 128;

  (void)hipMemsetAsync(flag, 0, 4, stream);
  zero_detect_kernel<<<gN, TB, 0, stream>>>(degcur, hists, rep, candcnt4, N, ei, flag, E);
  cvt_deg_kernel<<<gE, TB, 0, stream>>>(ei, flag, src32, dst32, degcur, E);
  scan_rowptr_kernel<<<1, 1024, 0, stream>>>(degcur, rowptr, N);
  scatter_kernel<<<gE, TB, 0, stream>>>(src32, degcur, eids, E);
  sort_eids_kernel<<<gN, TB, 0, stream>>>(rowptr, eids, N);
  wprep_kernel<<<56, 384, 0, stream>>>(W, a, wa_all, xw, wtH, wtM, wtL);
  et4_kernel<<<gE, TB, 0, stream>>>(ete, wa_all, et4, E);
  gemm_mfma_kernel<<<gM, 256, 0, stream>>>(x, nullptr, nullptr, nullptr, wtH, wtM, wtL, xb,
                                           xcA, N, 1, wa_all, pa, qa, nullptr, nullptr,
                                           nullptr, 1);

  float* bufs[2] = {xcA, xcB};
  for (int it = 0; it < 4; ++it) {
    const float* xc = bufs[it & 1];
    float* xn = bufs[(it & 1) ^ 1];
    unsigned* hists_it = hists + it * 1024;
    unsigned* rep_it = rep + it * 8192;
    unsigned* sres_it = scanres + it * 8;
    int* hdr_it = header + it * 80;
    const u16* wH = wtH + (size_t)(it + 1) * 12 * 4096;
    const u16* wM = wtM + (size_t)(it + 1) * 12 * 4096;
    const u16* wL = wtL + (size_t)(it + 1) * 12 * 4096;

    softmax_kernel<<<gN4, TB, 0, stream>>>(rowptr, eids, dst32, pa, qa, et4, it, E, alpha,
                                           rep_it, N);
    hist1_kernel<<<384, 256, 0, stream>>>(alpha, rep_it, hists_it, sres_it, Ktop, E);
    hist2_kernel<<<384, 256, 0, stream>>>(alpha, hists_it, sres_it, E);
    hist3c_kernel<<<384, 256, 0, stream>>>(alpha, hists_it, sres_it, candList,
                                           candcnt4 + it, E);
    resolve24_kernel<<<1, 1024, 0, stream>>>(alpha, amask, hists_it, sres_it, candList,
                                             candcnt4 + it, hdr_it, E);
    agg_kernel<<<gN4, TB, 0, stream>>>(rowptr, eids, dst32, alpha, amask, hdr_it,
                                       xc, ete, sa, vbuf, tbuf, N);
    if (it < 3)
      gemm_mfma_kernel<<<gM, 256, 0, stream>>>(xc, vbuf, tbuf, sa, wH, wM, wL, nullptr, xn,
                                               N, 3, wa_all + (it + 1) * 384, pa, qa,
                                               nullptr, nullptr, nullptr, 1);
    else
      gemm_mfma_kernel<<<gM, 256, 0, stream>>>(xc, vbuf, tbuf, sa, wH, wM, wL, nullptr, xn,
                                               N, 3, nullptr, pa, qa, gamma, beta, out, 2);
  }
}

// Round 11
// 824.255 us; speedup vs baseline: 1.6978x; 1.0355x over previous
//
#include <hip/hip_runtime.h>
#include <math.h>

#define DOUT 128

typedef unsigned short u16;
typedef __attribute__((ext_vector_type(8))) short bf16x8;   // 8 bf16 bit-patterns (4 VGPRs)
typedef __attribute__((ext_vector_type(4))) float f32x4;

static __device__ __forceinline__ f32x4 mfma16x16x32(bf16x8 a, bf16x8 b, f32x4 c) {
  return __builtin_amdgcn_mfma_f32_16x16x32_bf16(a, b, c, 0, 0, 0);
}

static __device__ __forceinline__ short bf16i(int v) {   // exact for |v| <= 256
  return (short)(__float_as_uint((float)v) >> 16);
}

// ---------- wave (64-lane) reductions ----------
static __device__ __forceinline__ float wsum64(float v) {
#pragma unroll
  for (int off = 32; off > 0; off >>= 1) v += __shfl_xor(v, off, 64);
  return v;
}
static __device__ __forceinline__ float wmax64(float v) {
#pragma unroll
  for (int off = 32; off > 0; off >>= 1) v = fmaxf(v, __shfl_xor(v, off, 64));
  return v;
}
// sum across the 4 lanes sharing (lane&15)  (lane bits 4,5)
static __device__ __forceinline__ float rsumg(float v) {
  v += __shfl_xor(v, 16, 64);
  v += __shfl_xor(v, 32, 64);
  return v;
}

// 3-way RNE bf16 split: x == h + m + l + eps, |eps| <= 2^-25 |x|  (manual, cold path)
static __device__ __forceinline__ void split3(float x, u16& h, u16& m, u16& l) {
  unsigned u = __float_as_uint(x);
  unsigned rh = u + 0x7FFFu + ((u >> 16) & 1u);
  h = (u16)(rh >> 16);
  float hf = __uint_as_float(rh & 0xFFFF0000u);
  float d1 = x - hf;
  unsigned v = __float_as_uint(d1);
  unsigned rm = v + 0x7FFFu + ((v >> 16) & 1u);
  m = (u16)(rm >> 16);
  float mf = __uint_as_float(rm & 0xFFFF0000u);
  float d2 = d1 - mf;
  unsigned w2 = __float_as_uint(d2);
  unsigned rl = w2 + 0x7FFFu + ((w2 >> 16) & 1u);
  l = (u16)(rl >> 16);
}

// hot-path split via v_cvt_pk_bf16_f32 (HW RNE; packs lo=cvt(x0), hi=cvt(x1))
static __device__ __forceinline__ void split3pk(float x0, float x1,
                                                unsigned& h, unsigned& m, unsigned& l) {
  unsigned hp, mp, lp;
  asm("v_cvt_pk_bf16_f32 %0, %1, %2" : "=v"(hp) : "v"(x0), "v"(x1));
  float d0 = x0 - __uint_as_float(hp << 16);
  float d1 = x1 - __uint_as_float(hp & 0xFFFF0000u);
  asm("v_cvt_pk_bf16_f32 %0, %1, %2" : "=v"(mp) : "v"(d0), "v"(d1));
  float e0 = d0 - __uint_as_float(mp << 16);
  float e1 = d1 - __uint_as_float(mp & 0xFFFF0000u);
  asm("v_cvt_pk_bf16_f32 %0, %1, %2" : "=v"(lp) : "v"(e0), "v"(e1));
  h = hp; m = mp; l = lp;
}
static __device__ __forceinline__ void split34pk(float4 v, uint2& h, uint2& m, uint2& lo) {
  split3pk(v.x, v.y, h.x, m.x, lo.x);
  split3pk(v.z, v.w, h.y, m.y, lo.y);
}

// ---------- setup: zero deg/hists/replicas/candcnt + dtype detect (merged) ----------
__global__ void zero_detect_kernel(int* __restrict__ degcur, unsigned* __restrict__ hists,
                                   unsigned* __restrict__ rep, int* __restrict__ candcnt4,
                                   int N, const void* __restrict__ ei, int* __restrict__ flag,
                                   int E) {
  int i = blockIdx.x * blockDim.x + threadIdx.x;
  if (i < N) degcur[i] = 0;
  if (i < 4096) hists[i] = 0u;
  if (i < 32768) rep[i] = 0u;
  if (i < 4) candcnt4[i] = 0;
  const int* p = (const int*)ei;
  int lim = (E < 65536) ? E : 65536;
  int any = 0;
  for (int j = i; j < lim; j += gridDim.x * blockDim.x) any |= (p[2 * j + 1] != 0);
  if (__any(any))
    if ((threadIdx.x & 63) == 0 && any) atomicOr(flag, 1);
}

// ---------- cvt + degree count ----------
__global__ void cvt_deg_kernel(const void* __restrict__ ei, const int* __restrict__ flag,
                               int* __restrict__ src, int* __restrict__ dst,
                               int* __restrict__ degcur, int E) {
  int i = blockIdx.x * blockDim.x + threadIdx.x;
  if (i >= E) return;
  int s, d;
  if (*flag) { const int* p = (const int*)ei; s = p[i]; d = p[E + i]; }
  else { const long long* p = (const long long*)ei; s = (int)p[i]; d = (int)p[(size_t)E + i]; }
  src[i] = s;
  dst[i] = d;
  atomicAdd(&degcur[s], 1);
}

// ---------- rowptr scan (also leaves cursor copy in degcur) ----------
__global__ void scan_rowptr_kernel(int* __restrict__ degcur, int* __restrict__ rowptr, int N) {
  const int tid = threadIdx.x;  // 1024
  const int lane = tid & 63, wid = tid >> 6;
  __shared__ int wsumS[16];
  __shared__ int sbase;
  if (tid == 0) sbase = 0;
  __syncthreads();
  for (int base = 0; base < N; base += 1024) {
    int i = base + tid;
    int v = (i < N) ? degcur[i] : 0;
    int x = v;
#pragma unroll
    for (int off = 1; off < 64; off <<= 1) {
      int y = __shfl_up(x, off, 64);
      if (lane >= off) x += y;
    }
    if (lane == 63) wsumS[wid] = x;
    __syncthreads();
    int wbase = 0;
#pragma unroll
    for (int w2 = 0; w2 < 16; ++w2) wbase += (w2 < wid) ? wsumS[w2] : 0;
    int excl = sbase + wbase + x - v;
    if (i < N) { rowptr[i] = excl; degcur[i] = excl; }
    __syncthreads();
    if (tid == 1023) sbase += wbase + x;
    __syncthreads();
  }
  if (tid == 0) rowptr[N] = sbase;
}

__global__ void scatter_kernel(const int* __restrict__ src, int* __restrict__ cursor,
                               int* __restrict__ eids, int E) {
  int e = blockIdx.x * blockDim.x + threadIdx.x;
  if (e >= E) return;
  int p = atomicAdd(&cursor[src[e]], 1);
  eids[p] = e;
}

// ---------- determinism: sort each segment's edge ids ascending (thread/node) ----------
__global__ void sort_eids_kernel(const int* __restrict__ rowptr, int* __restrict__ eids, int N) {
  int n = blockIdx.x * blockDim.x + threadIdx.x;
  if (n >= N) return;
  int p0 = rowptr[n], p1 = rowptr[n + 1];
  for (int i = p0 + 1; i < p1; ++i) {
    int key = eids[i];
    int j = i - 1;
    while (j >= p0 && eids[j] > key) { eids[j + 1] = eids[j]; --j; }
    eids[j + 1] = key;
  }
}

// ---------- merged: wa_all (blocks 0..3) + weight pre-split/tile with mu perm (blocks 4..55) ----
// RUNTIME k-map calibration: 32 exact-integer MFMA probes measure mu(t) = hA^-1(hB(t)).
// Storing B slot t <- B[k=mu(t)] equalizes the effective k-permutations for ANY hA,hB.
__global__ void wprep_kernel(const float* __restrict__ W, const float* __restrict__ a,
                             float* __restrict__ wa_all, const float* __restrict__ xw,
                             u16* __restrict__ wtH, u16* __restrict__ wtM,
                             u16* __restrict__ wtL) {
  int blk = blockIdx.x;  // 0..55
  int tid = threadIdx.x; // 384
  if (blk < 4) {
    int it = blk, k = tid;
    const float* row = W + ((size_t)it * 384 + k) * DOUT;
    const float* ai = a + (size_t)it * DOUT;
    float acc = 0.f;
    for (int j = 0; j < DOUT; ++j) acc = fmaf(row[j], ai[j], acc);
    wa_all[it * 384 + k] = acc;
    return;
  }
  __shared__ int muS[32];
  {
    int lw = tid & 63, g = lw >> 4;
    bf16x8 aEnc;
#pragma unroll
    for (int j = 0; j < 8; ++j) aEnc[j] = bf16i(8 * g + j + 1);   // A-slot index encode
    f32x4 z = {0.f, 0.f, 0.f, 0.f};
    for (int t0 = 0; t0 < 32; ++t0) {
      int g0 = t0 >> 3, j0 = t0 & 7;
      bf16x8 bOne;
#pragma unroll
      for (int j = 0; j < 8; ++j)
        bOne[j] = (g == g0 && j == j0) ? (short)0x3F80 : (short)0;  // one-hot B slot t0
      f32x4 d = mfma16x16x32(aEnc, bOne, z);
      if (tid == t0) muS[t0] = ((int)(d[0] + 0.5f) - 1) & 31;
    }
  }
  __syncthreads();
  int b = blk - 4;  // 0..51
  int set, ks;
  const float* srcp;
  if (b < 4) { set = 0; ks = b; srcp = xw; }
  else { set = 1 + (b - 4) / 12; ks = (b - 4) % 12; srcp = W + (size_t)(set - 1) * 384 * DOUT; }
  size_t base = ((size_t)set * 12 + ks) * 4096;
  for (int i = tid; i < 4096; i += blockDim.x) {
    int col = i >> 5, t = i & 31;
    float x = srcp[(size_t)(ks * 32 + muS[t]) * DOUT + col];   // k pre-permuted by mu
    u16 h, m, l;
    split3(x, h, m, l);
    wtH[base + i] = h;
    wtM[base + i] = m;
    wtL[base + i] = l;
  }
}

// ---------- et4 in CSR order + edge-data permute:
// p-th CSR slot: e = eids[p]; et4[it*E+p] = ete[e]·wa3(it); dstp[p] = dst[e]; pos[e] = p.
// (contiguous writes; 512B row-random reads are granularity-harmless) ----------
__global__ __launch_bounds__(256) void et4_kernel(const float* __restrict__ ete,
                                                  const float* __restrict__ wa_all,
                                                  const int* __restrict__ eids,
                                                  const int* __restrict__ dst,
                                                  int* __restrict__ dstp, int* __restrict__ pos,
                                                  float* __restrict__ et4, int E) {
  __shared__ float4 w3s[4][32];
  int tid = threadIdx.x;
  if (tid < 128) {
    int it = tid >> 5, k4 = tid & 31;
    const float* base = wa_all + it * 384 + 256 + k4 * 4;
    w3s[it][k4] = make_float4(base[0], base[1], base[2], base[3]);
  }
  __syncthreads();
  int p = blockIdx.x * blockDim.x + tid;
  if (p >= E) return;
  int e = eids[p];
  dstp[p] = dst[e];
  pos[e] = p;
  const float4* row = (const float4*)(ete + (size_t)e * DOUT);
  float a0 = 0.f, a1 = 0.f, a2 = 0.f, a3 = 0.f;
#pragma unroll
  for (int k4 = 0; k4 < 32; ++k4) {
    float4 r = row[k4];
    float4 w0 = w3s[0][k4], w1 = w3s[1][k4], w2 = w3s[2][k4], w3v = w3s[3][k4];
    a0 = fmaf(r.x, w0.x, fmaf(r.y, w0.y, fmaf(r.z, w0.z, fmaf(r.w, w0.w, a0))));
    a1 = fmaf(r.x, w1.x, fmaf(r.y, w1.y, fmaf(r.z, w1.z, fmaf(r.w, w1.w, a1))));
    a2 = fmaf(r.x, w2.x, fmaf(r.y, w2.y, fmaf(r.z, w2.z, fmaf(r.w, w2.w, a2))));
    a3 = fmaf(r.x, w3v.x, fmaf(r.y, w3v.y, fmaf(r.z, w3v.z, fmaf(r.w, w3v.w, a3))));
  }
  et4[p] = a0;
  et4[(size_t)E + p] = a1;
  et4[(size_t)2 * E + p] = a2;
  et4[(size_t)3 * E + p] = a3;
}

// ---------- fused score + segment softmax + REPLICATED hist level 0 (CSR-ordered) ----------
// alpha/etp/dstp all indexed by CSR position p -> fully contiguous per-node accesses.
// Per-node edge order (ascending e) is unchanged -> bit-identical alpha values.
__global__ __launch_bounds__(256) void softmax_kernel(
    const int* __restrict__ rowptr, const int* __restrict__ dstp,
    const float* __restrict__ pa, const float* __restrict__ qa, const float* __restrict__ et4,
    int it, int E, float* __restrict__ alpha, unsigned* __restrict__ rep0, int N) {
  __shared__ unsigned lh[256];
  int tid = threadIdx.x;
  lh[tid] = 0u;
  __syncthreads();
  const float* etp = et4 + (size_t)it * E;
  int w = (int)(((size_t)blockIdx.x * blockDim.x + tid) >> 6);
  int lane = tid & 63;
  if (w < N) {
    int p0 = rowptr[w], p1 = rowptr[w + 1];
    int deg = p1 - p0;
    if (deg > 0) {
      float pan = pa[w];
      if (deg <= 64) {
        int p = p0 + lane;
        int ok = (p < p1);
        float sv = -3.402823466e38f;
        if (ok) {
          float s = pan + qa[dstp[p]] + etp[p];
          sv = (s >= 0.f) ? s : 0.2f * s;
        }
        float m = wmax64(sv);
        float ee = ok ? expf(sv - m) : 0.f;
        float den = 0.f;
        for (int i = 0; i < deg; ++i) den += __shfl(ee, i, 64);  // ordered sum
        den += 1e-16f;
        if (ok) {
          float av = ee / den;
          alpha[p] = av;
          atomicAdd(&lh[__float_as_uint(av) >> 24], 1u);
        }
      } else if (deg <= 256) {
        float sv[4]; int okv[4];
#pragma unroll
        for (int u = 0; u < 4; ++u) {
          int p = p0 + u * 64 + lane;
          if (p < p1) {
            okv[u] = 1;
            float s = pan + qa[dstp[p]] + etp[p];
            sv[u] = (s >= 0.f) ? s : 0.2f * s;
          } else { okv[u] = 0; sv[u] = -3.402823466e38f; }
        }
        float m = fmaxf(fmaxf(sv[0], sv[1]), fmaxf(sv[2], sv[3]));
        m = wmax64(m);
        float ssum = 0.f;
#pragma unroll
        for (int u = 0; u < 4; ++u)
          if (okv[u]) { sv[u] = expf(sv[u] - m); ssum += sv[u]; }
        ssum = wsum64(ssum);
        float den = ssum + 1e-16f;
#pragma unroll
        for (int u = 0; u < 4; ++u)
          if (okv[u]) {
            float av = sv[u] / den;
            alpha[p0 + u * 64 + lane] = av;
            atomicAdd(&lh[__float_as_uint(av) >> 24], 1u);
          }
      } else {
        float m = -3.402823466e38f;
        for (int p = p0 + lane; p < p1; p += 64) {
          float s = pan + qa[dstp[p]] + etp[p];
          s = (s >= 0.f) ? s : 0.2f * s;
          m = fmaxf(m, s);
        }
        m = wmax64(m);
        float ssum = 0.f;
        for (int p = p0 + lane; p < p1; p += 64) {
          float s = pan + qa[dstp[p]] + etp[p];
          s = (s >= 0.f) ? s : 0.2f * s;
          ssum += expf(s - m);
        }
        ssum = wsum64(ssum);
        float den = ssum + 1e-16f;
        for (int p = p0 + lane; p < p1; p += 64) {
          float s = pan + qa[dstp[p]] + etp[p];
          s = (s >= 0.f) ? s : 0.2f * s;
          float av = expf(s - m) / den;
          alpha[p] = av;
          atomicAdd(&lh[__float_as_uint(av) >> 24], 1u);
        }
      }
    }
  }
  __syncthreads();
  if (lh[tid]) atomicAdd(&rep0[(blockIdx.x & 31) * 256 + tid], lh[tid]);
}

// ---------- single-level 256-bin scan (reads hist via plain loads) ----------
__device__ __forceinline__ void scan256_one(const unsigned* __restrict__ hist, unsigned krem_in,
                                            unsigned* lds, unsigned* res,
                                            unsigned& bin, unsigned& krem_out) {
  int t = threadIdx.x;
  lds[t] = hist[t];
  __syncthreads();
  for (int off = 1; off < 256; off <<= 1) {
    unsigned add = (t + off < 256) ? lds[t + off] : 0u;
    __syncthreads();
    lds[t] += add;
    __syncthreads();
  }
  {
    unsigned above = (t == 255) ? 0u : lds[t + 1];
    if (lds[t] >= krem_in && above < krem_in) { res[0] = (unsigned)t; res[1] = krem_in - above; }
  }
  __syncthreads();
  bin = res[0];
  krem_out = res[1];
  __syncthreads();
}

// ---------- hist1: reduce 32 replicas -> level-0 scan; write scanres0; build level-1 ----------
__global__ __launch_bounds__(256) void hist1_kernel(const float* __restrict__ alpha,
                                                    const unsigned* __restrict__ rep0,
                                                    unsigned* __restrict__ hists_it,
                                                    unsigned* __restrict__ scanres,
                                                    unsigned Ktop, int E) {
  __shared__ unsigned lds[256], res2[2], lh[256];
  int t = threadIdx.x;
  unsigned v = 0u;
#pragma unroll
  for (int r = 0; r < 32; ++r) v += rep0[r * 256 + t];
  lds[t] = v;
  __syncthreads();
  for (int off = 1; off < 256; off <<= 1) {
    unsigned add = (t + off < 256) ? lds[t + off] : 0u;
    __syncthreads();
    lds[t] += add;
    __syncthreads();
  }
  {
    unsigned above = (t == 255) ? 0u : lds[t + 1];
    if (lds[t] >= Ktop && above < Ktop) { res2[0] = (unsigned)t; res2[1] = Ktop - above; }
  }
  __syncthreads();
  unsigned bin0 = res2[0];
  if (blockIdx.x == 0 && t == 0) { scanres[0] = bin0; scanres[1] = res2[1]; }
  lh[t] = 0u;
  __syncthreads();
  unsigned* myh = hists_it + 256;
  for (int e = blockIdx.x * blockDim.x + t; e < E; e += gridDim.x * blockDim.x) {
    unsigned b = __float_as_uint(alpha[e]);
    if ((b >> 24) == bin0) atomicAdd(&lh[(b >> 16) & 0xFFu], 1u);
  }
  __syncthreads();
  if (lh[t]) atomicAdd(&myh[t], lh[t]);
}

// ---------- hist2: scan level-1 (using scanres0); write scanres1; build level-2 ----------
__global__ __launch_bounds__(256) void hist2_kernel(const float* __restrict__ alpha,
                                                    unsigned* __restrict__ hists_it,
                                                    unsigned* __restrict__ scanres, int E) {
  __shared__ unsigned lds[256], res2[2], lh[256];
  int t = threadIdx.x;
  unsigned pref8 = scanres[0], krem0 = scanres[1];
  unsigned bin1, krem1;
  scan256_one(hists_it + 256, krem0, lds, res2, bin1, krem1);
  unsigned pref16 = (pref8 << 8) | bin1;
  if (blockIdx.x == 0 && t == 0) { scanres[2] = pref16; scanres[3] = krem1; }
  lh[t] = 0u;
  __syncthreads();
  unsigned* myh = hists_it + 512;
  for (int e = blockIdx.x * blockDim.x + t; e < E; e += gridDim.x * blockDim.x) {
    unsigned b = __float_as_uint(alpha[e]);
    if ((b >> 16) == pref16) atomicAdd(&lh[(b >> 8) & 0xFFu], 1u);
  }
  __syncthreads();
  if (lh[t]) atomicAdd(&myh[t], lh[t]);
}

// ---------- hist3 + collect: scan level-2; write scanres2; build level-3 + candidates ----------
// candList stores CSR positions p.
__global__ __launch_bounds__(256) void hist3c_kernel(const float* __restrict__ alpha,
                                                     unsigned* __restrict__ hists_it,
                                                     unsigned* __restrict__ scanres,
                                                     int* __restrict__ candList,
                                                     int* __restrict__ candCnt, int E) {
  __shared__ unsigned lds[256], res2[2], lh[256];
  int t = threadIdx.x;
  unsigned pref16 = scanres[2], krem1 = scanres[3];
  unsigned bin2, krem2;
  scan256_one(hists_it + 512, krem1, lds, res2, bin2, krem2);
  unsigned pref24 = (pref16 << 8) | bin2;
  if (blockIdx.x == 0 && t == 0) { scanres[4] = pref24; scanres[5] = krem2; }
  lh[t] = 0u;
  __syncthreads();
  unsigned* myh = hists_it + 768;
  for (int e = blockIdx.x * blockDim.x + t; e < E; e += gridDim.x * blockDim.x) {
    unsigned b = __float_as_uint(alpha[e]);
    if ((b >> 8) == pref24) {
      atomicAdd(&lh[b & 0xFFu], 1u);
      int p = atomicAdd(candCnt, 1);
      if (p < 4096) candList[p] = e;
    }
  }
  __syncthreads();
  if (lh[t]) atomicAdd(&myh[t], lh[t]);
}

// ---------- resolve24 (1 block): scan level-3; thr + tiny drop-list (ORIGINAL edge ids);
// adversarial fallback walks e-order via pos[] for reference-identical tie ranking ----------
__global__ __launch_bounds__(1024) void resolve24_kernel(
    const float* __restrict__ alpha, float* __restrict__ amask,
    const unsigned* __restrict__ hists_it, const unsigned* __restrict__ scanres,
    const int* __restrict__ candList, const int* __restrict__ candCnt,
    const int* __restrict__ eids, const int* __restrict__ pos,
    int* __restrict__ header, int E) {
  __shared__ unsigned lds[256], res2[2];
  int tid = threadIdx.x;
  unsigned pref24 = scanres[4], krem2 = scanres[5];
  {
    int t = tid;
    if (t < 256) lds[t] = hists_it[768 + t];
    __syncthreads();
    for (int off = 1; off < 256; off <<= 1) {
      unsigned add = 0u;
      if (t < 256 && t + off < 256) add = lds[t + off];
      __syncthreads();
      if (t < 256) lds[t] += add;
      __syncthreads();
    }
    if (t < 256) {
      unsigned above = (t == 255) ? 0u : lds[t + 1];
      if (lds[t] >= krem2 && above < krem2) { res2[0] = (unsigned)t; res2[1] = krem2 - above; }
    }
    __syncthreads();
  }
  unsigned thr = (pref24 << 8) | res2[0];
  int needT = (int)res2[1];
  __syncthreads();
  int cc = *candCnt;
  __shared__ int tiel[4096];
  __shared__ int tiec;
  if (tid == 0) tiec = 0;
  __syncthreads();
  if (cc <= 4096) {
    for (int i = tid; i < cc; i += blockDim.x) {
      int p = candList[i];
      if (__float_as_uint(alpha[p]) == thr) {
        int q = atomicAdd(&tiec, 1);
        tiel[q] = eids[p];   // original edge id (tie ranking is by e, as in reference)
      }
    }
    __syncthreads();
    int ce = tiec;
    int dropc = ce - needT;
    if (dropc <= 0) {
      if (tid == 0) { header[0] = 0; header[1] = (int)thr; header[2] = 0; }
      return;
    }
    if (dropc <= 64) {
      int sortN = 64;
      while (sortN < ce) sortN <<= 1;
      for (int i = tid; i < sortN; i += blockDim.x)
        if (i >= ce) tiel[i] = 0x7fffffff;
      __syncthreads();
      for (int k = 2; k <= sortN; k <<= 1) {
        for (int j = k >> 1; j > 0; j >>= 1) {
          for (int i = tid; i < sortN; i += blockDim.x) {
            int ixj = i ^ j;
            if (ixj > i) {
              int v0 = tiel[i], v1 = tiel[ixj];
              bool up = ((i & k) == 0);
              if ((v0 > v1) == up) { tiel[i] = v1; tiel[ixj] = v0; }
            }
          }
          __syncthreads();
        }
      }
      if (tid == 0) { header[0] = 0; header[1] = (int)thr; header[2] = dropc; }
      for (int i = tid; i < dropc; i += blockDim.x) header[3 + i] = tiel[needT + i];
      return;
    }
  }
  // adversarial fallback: write FULL amask[e] deterministically in e-order (slow but correct)
  if (tid == 0) { header[0] = 1; }
  __shared__ int wtot[16];
  __shared__ int sbase;
  if (tid == 0) sbase = 0;
  __syncthreads();
  int lane = tid & 63, wid = tid >> 6;
  for (int base = 0; base < E; base += 1024) {
    int e = base + tid;
    float a = 0.f; int f = 0; unsigned b = 0u;
    if (e < E) { a = alpha[pos[e]]; b = __float_as_uint(a); f = (b == thr) ? 1 : 0; }
    int x = f;
#pragma unroll
    for (int off = 1; off < 64; off <<= 1) {
      int y = __shfl_up(x, off, 64);
      if (lane >= off) x += y;
    }
    if (lane == 63) wtot[wid] = x;
    __syncthreads();
    int wbase = 0;
#pragma unroll
    for (int w2 = 0; w2 < 16; ++w2) wbase += (w2 < wid) ? wtot[w2] : 0;
    if (e < E) {
      float outv = 0.f;
      if (b > thr) outv = a;
      else if (f && (sbase + wbase + x - f) < needT) outv = a;
      amask[e] = outv;
    }
    __syncthreads();
    if (tid == 1023) sbase += wbase + x;
    __syncthreads();
  }
}

// ---------- per-edge weight from CSR-ordered alpha value (flag=1 -> amask[e] fallback) ----------
static __device__ __forceinline__ float edge_w2(float av, const float* __restrict__ amask,
                                                const int* __restrict__ hdr, int flg,
                                                unsigned thr, int dc, int e) {
  if (flg) return amask[e];
  unsigned b = __float_as_uint(av);
  if (b > thr) return av;
  if (b == thr) {
    for (int j = 0; j < dc; ++j)
      if (hdr[3 + j] == e) return 0.f;
    return av;
  }
  return 0.f;
}

// ---------- aggregation (wave per node, split halves; CSR-contiguous metadata) ----------
__global__ void agg_kernel(const int* __restrict__ rowptr, const int* __restrict__ eids,
                           const int* __restrict__ dstp, const float* __restrict__ alpha,
                           const float* __restrict__ amask, const int* __restrict__ hdr,
                           const float* __restrict__ xc, const float* __restrict__ ete,
                           float* __restrict__ sa, float* __restrict__ vbuf,
                           float* __restrict__ tbuf, int N) {
  int w = (int)(((size_t)blockIdx.x * blockDim.x + threadIdx.x) >> 6);
  int lane = threadIdx.x & 63;
  if (w >= N) return;
  const int flg = hdr[0];
  const unsigned thr = (unsigned)hdr[1];
  const int dc = hdr[2];
  int p0 = rowptr[w], p1 = rowptr[w + 1];
  int deg = p1 - p0;
  const int half = lane >> 5;
  const int l32 = lane & 31;
  const float4* xc4 = (const float4*)xc;
  const float4* et4p = (const float4*)ete;
  float4 acc = make_float4(0.f, 0.f, 0.f, 0.f);
  float s = 0.f;
  if (deg <= 64) {
    int p = p0 + lane;
    int e = -1; float am = 0.f; int dd = 0;
    if (p < p1) { e = eids[p]; am = edge_w2(alpha[p], amask, hdr, flg, thr, dc, e); dd = dstp[p]; }
    for (int i = 0; i < deg; ++i) {
      float a = __shfl(am, i, 64);
      if (a != 0.f) {
        int ei = __shfl(e, i, 64);
        int di = __shfl(dd, i, 64);
        const float4* b = half ? (et4p + (size_t)ei * 32) : (xc4 + (size_t)di * 32);
        float4 r = b[l32];
        acc.x = fmaf(a, r.x, acc.x); acc.y = fmaf(a, r.y, acc.y);
        acc.z = fmaf(a, r.z, acc.z); acc.w = fmaf(a, r.w, acc.w);
        s += a;
      }
    }
  } else {
    for (int p = p0; p < p1; ++p) {
      int e0 = eids[p];
      float a0 = edge_w2(alpha[p], amask, hdr, flg, thr, dc, e0);
      if (a0 != 0.f) {
        int d0 = dstp[p];
        const float4* b0 = half ? (et4p + (size_t)e0 * 32) : (xc4 + (size_t)d0 * 32);
        float4 r = b0[l32];
        acc.x = fmaf(a0, r.x, acc.x); acc.y = fmaf(a0, r.y, acc.y);
        acc.z = fmaf(a0, r.z, acc.z); acc.w = fmaf(a0, r.w, acc.w);
        s += a0;
      }
    }
  }
  if (half == 0) ((float4*)vbuf)[(size_t)w * 32 + l32] = acc;
  else           ((float4*)tbuf)[(size_t)w * 32 + l32] = acc;
  if (lane == 0) sa[w] = s;
}

// ---------- MFMA GEMM: C[Nx128] = concat(sca*A0|A1|A2)[N x 128*nseg] @ B (+bias)
// fp32 emulated via 3-way RNE bf16 split (6 product terms, residual ~2^-24 rel).
// SELF-CALIBRATING on all lane maps (k-maps via mu-permuted B; C/D via in-kernel probes
// + measured-map LDS slab epilogue).  cvt_pk hot split + 1-step register prefetch.
//            epi=1: fused pa/qa for next iter;  epi=2: fused ELU+LayerNorm -> outp ----------
__global__ __launch_bounds__(256) void gemm_mfma_kernel(
    const float* __restrict__ A0, const float* __restrict__ A1, const float* __restrict__ A2,
    const float* __restrict__ sca, const u16* __restrict__ wtH, const u16* __restrict__ wtM,
    const u16* __restrict__ wtL, const float* __restrict__ bias, float* __restrict__ C,
    int N, int nseg,
    const float* __restrict__ wa_next, float* __restrict__ pa, float* __restrict__ qa,
    const float* __restrict__ gamma, const float* __restrict__ beta,
    float* __restrict__ outp, int epi) {
  __shared__ __align__(16) char smem[61440];
  u16 (*AsH)[40] = (u16(*)[40])(smem);
  u16 (*AsM)[40] = (u16(*)[40])(smem + 10240);
  u16 (*AsL)[40] = (u16(*)[40])(smem + 20480);
  u16 (*BsH)[40] = (u16(*)[40])(smem + 30720);
  u16 (*BsM)[40] = (u16(*)[40])(smem + 40960);
  u16 (*BsL)[40] = (u16(*)[40])(smem + 51200);
  const int tid = threadIdx.x;
  const int m0 = blockIdx.x * 128;
  const int K = DOUT * nseg;
  const int w = tid >> 6, l = tid & 63;
  const int cb = l & 15, g = l >> 4;

  // --- C/D lane-map calibration (2 exact-integer MFMAs) ---
  int rowlab[4], collab[4];
  {
    bf16x8 enc, ones;
#pragma unroll
    for (int j = 0; j < 8; ++j) { enc[j] = bf16i(cb + 1); ones[j] = (short)0x3F80; }
    f32x4 z = {0.f, 0.f, 0.f, 0.f};
    f32x4 dR = mfma16x16x32(enc, ones, z);   // D = 32*(row+1)
    f32x4 dC = mfma16x16x32(ones, enc, z);   // D = 32*(col+1)
#pragma unroll
    for (int r = 0; r < 4; ++r) {
      rowlab[r] = ((int)(dR[r] * (1.f / 32.f) + 0.5f) - 1) & 15;
      collab[r] = ((int)(dC[r] * (1.f / 32.f) + 0.5f) - 1) & 15;
    }
  }

  f32x4 acc[2][8];
#pragma unroll
  for (int i = 0; i < 2; ++i)
#pragma unroll
    for (int j = 0; j < 8; ++j) acc[i][j] = (f32x4){0.f, 0.f, 0.f, 0.f};

  // staging role: thread handles A row (tid>>1), 16 floats at col half*16
  const int srow = tid >> 1, shalf = tid & 1;
  const int grow_s = m0 + srow;
  float scv = 1.f;
  if (sca && grow_s < N) scv = sca[grow_s];

  auto loadA = [&](int kc, float4& v0, float4& v1, float4& v2, float4& v3) {
    const int seg = kc >> 7;
    const float* Ap = (seg == 0) ? A0 : (seg == 1) ? A1 : A2;
    v0 = make_float4(0.f, 0.f, 0.f, 0.f); v1 = v0; v2 = v0; v3 = v0;
    if (grow_s < N) {
      const float4* p = (const float4*)(Ap + (size_t)grow_s * DOUT + (kc & 127) + shalf * 16);
      v0 = p[0]; v1 = p[1]; v2 = p[2]; v3 = p[3];
      if (seg == 0 && sca) {
        v0.x *= scv; v0.y *= scv; v0.z *= scv; v0.w *= scv;
        v1.x *= scv; v1.y *= scv; v1.z *= scv; v1.w *= scv;
        v2.x *= scv; v2.y *= scv; v2.z *= scv; v2.w *= scv;
        v3.x *= scv; v3.y *= scv; v3.z *= scv; v3.w *= scv;
      }
    }
  };
  auto loadB = [&](int kc, uint4& h0, uint4& h1, uint4& m0u, uint4& m1u, uint4& l0u,
                   uint4& l1u) {
    size_t sb = (size_t)(kc >> 5) << 12;
    const uint4* gh = (const uint4*)(wtH + sb) + tid * 2;
    const uint4* gm = (const uint4*)(wtM + sb) + tid * 2;
    const uint4* gl = (const uint4*)(wtL + sb) + tid * 2;
    h0 = gh[0]; h1 = gh[1];
    m0u = gm[0]; m1u = gm[1];
    l0u = gl[0]; l1u = gl[1];
  };

  float4 av0, av1, av2, av3, nv0, nv1, nv2, nv3;
  uint4 bh0, bh1, bm0u, bm1u, bl0u, bl1u, nh0, nh1, nm0, nm1, nl0, nl1;
  loadA(0, av0, av1, av2, av3);
  loadB(0, bh0, bh1, bm0u, bm1u, bl0u, bl1u);

  const int nks = K >> 5;
  for (int ks = 0; ks < nks; ++ks) {
    const int kc = ks << 5;
    {
      uint2 h0, m0v, l0, h1, m1v, l1, h2, m2v, l2, h3, m3v, l3;
      split34pk(av0, h0, m0v, l0); split34pk(av1, h1, m1v, l1);
      split34pk(av2, h2, m2v, l2); split34pk(av3, h3, m3v, l3);
      *(uint4*)&AsH[srow][shalf * 16]     = make_uint4(h0.x, h0.y, h1.x, h1.y);
      *(uint4*)&AsH[srow][shalf * 16 + 8] = make_uint4(h2.x, h2.y, h3.x, h3.y);
      *(uint4*)&AsM[srow][shalf * 16]     = make_uint4(m0v.x, m0v.y, m1v.x, m1v.y);
      *(uint4*)&AsM[srow][shalf * 16 + 8] = make_uint4(m2v.x, m2v.y, m3v.x, m3v.y);
      *(uint4*)&AsL[srow][shalf * 16]     = make_uint4(l0.x, l0.y, l1.x, l1.y);
      *(uint4*)&AsL[srow][shalf * 16 + 8] = make_uint4(l2.x, l2.y, l3.x, l3.y);
      *(uint4*)&BsH[srow][shalf * 16]     = bh0;
      *(uint4*)&BsH[srow][shalf * 16 + 8] = bh1;
      *(uint4*)&BsM[srow][shalf * 16]     = bm0u;
      *(uint4*)&BsM[srow][shalf * 16 + 8] = bm1u;
      *(uint4*)&BsL[srow][shalf * 16]     = bl0u;
      *(uint4*)&BsL[srow][shalf * 16 + 8] = bl1u;
    }
    if (ks + 1 < nks) {
      loadA(kc + 32, nv0, nv1, nv2, nv3);
      loadB(kc + 32, nh0, nh1, nm0, nm1, nl0, nl1);
    }
    __syncthreads();
    bf16x8 aH0 = *(const bf16x8*)&AsH[w * 32 + cb][g * 8];
    bf16x8 aH1 = *(const bf16x8*)&AsH[w * 32 + 16 + cb][g * 8];
    bf16x8 aM0 = *(const bf16x8*)&AsM[w * 32 + cb][g * 8];
    bf16x8 aM1 = *(const bf16x8*)&AsM[w * 32 + 16 + cb][g * 8];
    bf16x8 aL0 = *(const bf16x8*)&AsL[w * 32 + cb][g * 8];
    bf16x8 aL1 = *(const bf16x8*)&AsL[w * 32 + 16 + cb][g * 8];
#pragma unroll
    for (int ct = 0; ct < 8; ++ct) {
      bf16x8 bH = *(const bf16x8*)&BsH[ct * 16 + cb][g * 8];
      bf16x8 bM = *(const bf16x8*)&BsM[ct * 16 + cb][g * 8];
      bf16x8 bL = *(const bf16x8*)&BsL[ct * 16 + cb][g * 8];
      acc[0][ct] = mfma16x16x32(aH0, bH, acc[0][ct]);
      acc[1][ct] = mfma16x16x32(aH1, bH, acc[1][ct]);
      acc[0][ct] = mfma16x16x32(aM0, bH, acc[0][ct]);
      acc[1][ct] = mfma16x16x32(aM1, bH, acc[1][ct]);
      acc[0][ct] = mfma16x16x32(aL0, bH, acc[0][ct]);
      acc[1][ct] = mfma16x16x32(aL1, bH, acc[1][ct]);
      acc[0][ct] = mfma16x16x32(aH0, bM, acc[0][ct]);
      acc[1][ct] = mfma16x16x32(aH1, bM, acc[1][ct]);
      acc[0][ct] = mfma16x16x32(aM0, bM, acc[0][ct]);
      acc[1][ct] = mfma16x16x32(aM1, bM, acc[1][ct]);
      acc[0][ct] = mfma16x16x32(aH0, bL, acc[0][ct]);
      acc[1][ct] = mfma16x16x32(aH1, bL, acc[1][ct]);
    }
    __syncthreads();
    av0 = nv0; av1 = nv1; av2 = nv2; av3 = nv3;
    bh0 = nh0; bh1 = nh1; bm0u = nm0; bm1u = nm1; bl0u = nl0; bl1u = nl1;
  }

  // ---- epilogue: measured-map scatter into per-wave LDS slab, canonical read-back ----
  float* slab = (float*)(smem + (size_t)w * 8448);  // [16][132] f32
  const int row16 = l & 15;
  const int csel = (l >> 4) * 32;
#pragma unroll
  for (int rt = 0; rt < 2; ++rt) {
#pragma unroll
    for (int ct = 0; ct < 8; ++ct)
#pragma unroll
      for (int r = 0; r < 4; ++r)
        slab[rowlab[r] * 132 + ct * 16 + collab[r]] = acc[rt][ct][r];
    __syncthreads();
    int grow = m0 + w * 32 + rt * 16 + row16;
    float v[32];
#pragma unroll
    for (int q = 0; q < 8; ++q) {
      float4 t4 = *(float4*)&slab[row16 * 132 + csel + q * 4];
      v[q * 4 + 0] = t4.x; v[q * 4 + 1] = t4.y; v[q * 4 + 2] = t4.z; v[q * 4 + 3] = t4.w;
    }
    if (bias) {
#pragma unroll
      for (int q = 0; q < 8; ++q) {
        float4 bb = *(const float4*)(bias + csel + q * 4);
        v[q * 4 + 0] += bb.x; v[q * 4 + 1] += bb.y; v[q * 4 + 2] += bb.z; v[q * 4 + 3] += bb.w;
      }
    }
    if (epi == 2) {  // ELU + LayerNorm -> outp
#pragma unroll
      for (int i = 0; i < 32; ++i) v[i] = (v[i] > 0.f) ? v[i] : expm1f(v[i]);
      float s = 0.f;
#pragma unroll
      for (int i = 0; i < 32; ++i) s += v[i];
      s = rsumg(s);
      float mu = s * (1.f / 128.f);
      float sq = 0.f;
#pragma unroll
      for (int i = 0; i < 32; ++i) { float d = v[i] - mu; sq += d * d; }
      sq = rsumg(sq);
      float rstd = rsqrtf(sq * (1.f / 128.f) + 1e-5f);
      if (grow < N) {
#pragma unroll
        for (int q = 0; q < 8; ++q) {
          float4 ga = *(const float4*)(gamma + csel + q * 4);
          float4 be = *(const float4*)(beta + csel + q * 4);
          float4 o;
          o.x = (v[q * 4 + 0] - mu) * rstd * ga.x + be.x;
          o.y = (v[q * 4 + 1] - mu) * rstd * ga.y + be.y;
          o.z = (v[q * 4 + 2] - mu) * rstd * ga.z + be.z;
          o.w = (v[q * 4 + 3] - mu) * rstd * ga.w + be.w;
          *(float4*)(outp + (size_t)grow * DOUT + csel + q * 4) = o;
        }
      }
    } else {
      if (grow < N) {
#pragma unroll
        for (int q = 0; q < 8; ++q)
          *(float4*)(C + (size_t)grow * DOUT + csel + q * 4) =
              make_float4(v[q * 4 + 0], v[q * 4 + 1], v[q * 4 + 2], v[q * 4 + 3]);
      }
      if (epi == 1) {  // pa/qa for next iteration's scores
        float pp = 0.f, qq = 0.f;
#pragma unroll
        for (int i = 0; i < 32; ++i) {
          pp = fmaf(v[i], wa_next[csel + i], pp);
          qq = fmaf(v[i], wa_next[128 + csel + i], qq);
        }
        pp = rsumg(pp);
        qq = rsumg(qq);
        if ((l >> 4) == 0 && grow < N) { pa[grow] = pp; qa[grow] = qq; }
      }
    }
    __syncthreads();
  }
}

extern "C" void kernel_launch(void* const* d_in, const int* in_sizes, int n_in,
                              void* d_out, int out_size, void* d_ws, size_t ws_size,
                              hipStream_t stream) {
  const int E = in_sizes[0] / 2;
  const int N = in_sizes[1] / DOUT;
  const unsigned Ktop = (unsigned)(E / 2);  // int(E * 0.5)

  const void*  ei    = d_in[0];
  const float* x     = (const float*)d_in[1];
  const float* ete   = (const float*)d_in[2];
  const float* W     = (const float*)d_in[3];
  const float* a     = (const float*)d_in[4];
  const float* xw    = (const float*)d_in[5];
  const float* xb    = (const float*)d_in[6];
  const float* gamma = (const float*)d_in[7];
  const float* beta  = (const float*)d_in[8];
  float* out = (float*)d_out;

  size_t off = 0;
  auto take = [&](size_t bytes) -> char* {
    char* p = (char*)d_ws + off;
    off += (bytes + 255) & ~(size_t)255;
    return p;
  };
  int*      src32   = (int*)take((size_t)E * 4);
  int*      dst32   = (int*)take((size_t)E * 4);
  int*      rowptr  = (int*)take(((size_t)N + 1) * 4);
  int*      degcur  = (int*)take((size_t)N * 4);
  int*      eids    = (int*)take((size_t)E * 4);
  int*      dstp    = (int*)take((size_t)E * 4);
  int*      pos     = (int*)take((size_t)E * 4);
  float*    pa      = (float*)take((size_t)N * 4);
  float*    qa      = (float*)take((size_t)N * 4);
  float*    wa_all  = (float*)take(4 * 384 * 4);
  float*    alpha   = (float*)take((size_t)E * 4);
  float*    amask   = (float*)take((size_t)E * 4);
  float*    sa      = (float*)take((size_t)N * 4);
  float*    vbuf    = (float*)take((size_t)N * DOUT * 4);
  float*    tbuf    = (float*)take((size_t)N * DOUT * 4);
  float*    xcA     = (float*)take((size_t)N * DOUT * 4);
  float*    xcB     = (float*)take((size_t)N * DOUT * 4);
  float*    et4     = (float*)take((size_t)E * 4 * 4);
  unsigned* hists   = (unsigned*)take(4 * 4 * 256 * 4);   // [it][level][256]
  unsigned* rep     = (unsigned*)take(4 * 32 * 256 * 4);  // [it][replica][256]
  int*      candcnt4= (int*)take(64);
  int*      flag    = (int*)take(64);
  int*      candList= (int*)take(4096 * 4);
  int*      header  = (int*)take(4 * 80 * 4);             // [it][flag,thr,dropcnt,drops..]
  u16*      wtH     = (u16*)take((size_t)5 * 12 * 4096 * 2);  // pre-tiled bf16-hi weights
  u16*      wtM     = (u16*)take((size_t)5 * 12 * 4096 * 2);  // pre-tiled bf16-mid weights
  u16*      wtL     = (u16*)take((size_t)5 * 12 * 4096 * 2);  // pre-tiled bf16-lo weights
  unsigned* scanres = (unsigned*)take(4 * 8 * 4);         // [it][pref/krem per level]
  (void)ws_size; (void)n_in; (void)out_size;

  const int TB  = 256;
  const int gE  = (E + TB - 1) / TB;
  const int gN  = (N + TB - 1) / TB;
  const int gN4 = (N + 3) / 4;   // one wave per node
  const int gM  = (N + 127) / 128;

  (void)hipMemsetAsync(flag, 0, 4, stream);
  zero_detect_kernel<<<gN, TB, 0, stream>>>(degcur, hists, rep, candcnt4, N, ei, flag, E);
  cvt_deg_kernel<<<gE, TB, 0, stream>>>(ei, flag, src32, dst32, degcur, E);
  scan_rowptr_kernel<<<1, 1024, 0, stream>>>(degcur, rowptr, N);
  scatter_kernel<<<gE, TB, 0, stream>>>(src32, degcur, eids, E);
  sort_eids_kernel<<<gN, TB, 0, stream>>>(rowptr, eids, N);
  wprep_kernel<<<56, 384, 0, stream>>>(W, a, wa_all, xw, wtH, wtM, wtL);
  et4_kernel<<<gE, TB, 0, stream>>>(ete, wa_all, eids, dst32, dstp, pos, et4, E);
  gemm_mfma_kernel<<<gM, 256, 0, stream>>>(x, nullptr, nullptr, nullptr, wtH, wtM, wtL, xb,
                                           xcA, N, 1, wa_all, pa, qa, nullptr, nullptr,
                                           nullptr, 1);

  float* bufs[2] = {xcA, xcB};
  for (int it = 0; it < 4; ++it) {
    const float* xc = bufs[it & 1];
    float* xn = bufs[(it & 1) ^ 1];
    unsigned* hists_it = hists + it * 1024;
    unsigned* rep_it = rep + it * 8192;
    unsigned* sres_it = scanres + it * 8;
    int* hdr_it = header + it * 80;
    const u16* wH = wtH + (size_t)(it + 1) * 12 * 4096;
    const u16* wM = wtM + (size_t)(it + 1) * 12 * 4096;
    const u16* wL = wtL + (size_t)(it + 1) * 12 * 4096;

    softmax_kernel<<<gN4, TB, 0, stream>>>(rowptr, dstp, pa, qa, et4, it, E, alpha,
                                           rep_it, N);
    hist1_kernel<<<384, 256, 0, stream>>>(alpha, rep_it, hists_it, sres_it, Ktop, E);
    hist2_kernel<<<384, 256, 0, stream>>>(alpha, hists_it, sres_it, E);
    hist3c_kernel<<<384, 256, 0, stream>>>(alpha, hists_it, sres_it, candList,
                                           candcnt4 + it, E);
    resolve24_kernel<<<1, 1024, 0, stream>>>(alpha, amask, hists_it, sres_it, candList,
                                             candcnt4 + it, eids, pos, hdr_it, E);
    agg_kernel<<<gN4, TB, 0, stream>>>(rowptr, eids, dstp, alpha, amask, hdr_it,
                                       xc, ete, sa, vbuf, tbuf, N);
    if (it < 3)
      gemm_mfma_kernel<<<gM, 256, 0, stream>>>(xc, vbuf, tbuf, sa, wH, wM, wL, nullptr, xn,
                                               N, 3, wa_all + (it + 1) * 384, pa, qa,
                                               nullptr, nullptr, nullptr, 1);
    else
      gemm_mfma_kernel<<<gM, 256, 0, stream>>>(xc, vbuf, tbuf, sa, wH, wM, wL, nullptr, xn,
                                               N, 3, nullptr, pa, qa, gamma, beta, out, 2);
  }
}